// Round 5
// baseline (160.341 us; speedup 1.0000x reference)
//
#include <hip/hip_runtime.h>
#include <math.h>

#define N_TOK 4098
#define NK_TOK 4099
#define C_DIM 384
#define NKPAD 4160
#define NSLICE 6
// HEADS = 6, HD = 64

typedef short  bh8 __attribute__((ext_vector_type(8)));   // 8 bf16 (4 VGPRs)
typedef float  f32x4 __attribute__((ext_vector_type(4)));
typedef unsigned short ushort;
typedef ushort u4 __attribute__((ext_vector_type(4)));
typedef ushort u8 __attribute__((ext_vector_type(8)));

static __device__ __forceinline__ ushort f2bf(float f) {
  unsigned int u = __float_as_uint(f);
  u = (u + 0x7FFF + ((u >> 16) & 1)) >> 16;   // RNE
  return (ushort)u;
}
static __device__ __forceinline__ float bf2f(ushort s) {
  return __uint_as_float(((unsigned int)s) << 16);
}

// Q pre-scale: D^-0.5 * log2(e); attention exp computed as exp2
#define QSCALE 0.18033688011112042f

// ---------------------------------------------------------------------------
// pool partials (no atomics, no memset needed)
__global__ __launch_bounds__(384) void pool_kernel(
    const float* __restrict__ x, const float* __restrict__ mask,
    float* __restrict__ pooled_part, float* __restrict__ cnt_part) {
  const int b = blockIdx.x, t = threadIdx.x;
  const int r0 = b * 32;
  float acc = 0.f;
  int lc = 0;
  for (int r = r0; r < r0 + 32; ++r)
    if (mask[r] < 0.5f) { acc += x[(size_t)(r + 1) * C_DIM + t]; ++lc; }
  pooled_part[b * C_DIM + t] = acc;
  if (t == 0) cnt_part[b] = (float)lc;
}

// ---------------------------------------------------------------------------
// prep: blocks 0..259 build bf16 A-matrices (16 rows each); block 256 first
// reduces pool partials -> back token (row 4098). blocks 260..291 convert W.
// block 292: single-block keep-compaction prefix scan -> inv[], nk.
__global__ __launch_bounds__(256) void prep_kernel(
    const float* __restrict__ x, const float* __restrict__ pos,
    const float* __restrict__ pooled_part, const float* __restrict__ cnt_part,
    const float* __restrict__ Wq, const float* __restrict__ Wk,
    const float* __restrict__ Wv, const float* __restrict__ Wp,
    const float* __restrict__ mask, const float* __restrict__ mask_block,
    ushort* __restrict__ Aq, ushort* __restrict__ Ak, ushort* __restrict__ Av,
    ushort* __restrict__ Wb, int* __restrict__ nk, int* __restrict__ inv) {
  const int b = blockIdx.x, t = threadIdx.x;
  if (b < 260) {
    __shared__ float sback[C_DIM];
    if (b == 256) {                         // back token for row 4098
      float cs = 0.f;
      for (int i = (t & 63); i < 128; i += 64) cs += cnt_part[i];
#pragma unroll
      for (int d = 1; d < 64; d <<= 1) cs += __shfl_xor(cs, d);
      const float ic = 1.f / (cs + 1e-10f);
      for (int c = t; c < C_DIM; c += 256) {
        float s = 0.f;
        for (int p = 0; p < 128; ++p) s += pooled_part[p * C_DIM + c];
        sback[c] = s * ic;
      }
      __syncthreads();
    }
    const int r0 = b * 16;
#pragma unroll
    for (int i = 0; i < 6; ++i) {
      const int idx = i * 1024 + t * 4;
      const int row = r0 + idx / C_DIM, col = idx % C_DIM;
      if (row >= NK_TOK) continue;
      const float4 pv = *(const float4*)&pos[(size_t)row * C_DIM + col];
      float4 xv;
      if (row == NK_TOK - 1)
        xv = make_float4(sback[col], sback[col + 1], sback[col + 2], sback[col + 3]);
      else
        xv = *(const float4*)&x[(size_t)row * C_DIM + col];
      if (row < N_TOK) {
        u4 q4 = {f2bf((xv.x + pv.x) * QSCALE), f2bf((xv.y + pv.y) * QSCALE),
                 f2bf((xv.z + pv.z) * QSCALE), f2bf((xv.w + pv.w) * QSCALE)};
        *(u4*)&Aq[(size_t)row * C_DIM + col] = q4;
      }
      u4 k4 = {f2bf(xv.x + pv.x), f2bf(xv.y + pv.y),
               f2bf(xv.z + pv.z), f2bf(xv.w + pv.w)};
      *(u4*)&Ak[(size_t)row * C_DIM + col] = k4;
      u4 v4 = {f2bf(xv.x), f2bf(xv.y), f2bf(xv.z), f2bf(xv.w)};
      *(u4*)&Av[(size_t)row * C_DIM + col] = v4;
    }
  } else if (b < 292) {
    const int wi = b - 260;                  // 0..31; 8 blocks per weight
    const float* src = (wi < 8) ? Wq : (wi < 16) ? Wk : (wi < 24) ? Wv : Wp;
    const int base = (wi >> 3) * 147456 + (wi & 7) * 18432;
#pragma unroll 2
    for (int i = 0; i < 18; ++i) {
      const int g = base + i * 1024 + t * 4;
      const float4 v = *(const float4*)&src[(wi & 7) * 18432 + i * 1024 + t * 4];
      u4 o = {f2bf(v.x), f2bf(v.y), f2bf(v.z), f2bf(v.w)};
      *(u4*)&Wb[g] = o;
    }
  } else {
    // keep-compaction: 256 threads x 17 elements, block prefix scan
    __shared__ int scnt[256];
    const int j0 = t * 17;
    unsigned int bits = 0;
    int c = 0;
#pragma unroll 1
    for (int u = 0; u < 17; ++u) {
      const int j = j0 + u;
      bool keep = false;
      if (j < NK_TOK)
        keep = (j >= 1 && j <= N_TOK - 2) ? (mask[j - 1] >= 0.5f)
                                          : (mask_block[j] >= 0.5f);
      if (keep) { bits |= 1u << u; ++c; }
    }
    scnt[t] = c;
    __syncthreads();
    for (int d = 1; d < 256; d <<= 1) {
      const int v = scnt[t];
      const int add = (t >= d) ? scnt[t - d] : 0;
      __syncthreads();
      scnt[t] = v + add;
      __syncthreads();
    }
    int base = scnt[t] - c;                  // exclusive prefix
    if (t == 255) *nk = scnt[255];
#pragma unroll 1
    for (int u = 0; u < 17; ++u) {
      const int j = j0 + u;
      if (j < NK_TOK) inv[j] = ((bits >> u) & 1) ? base++ : -1;
    }
  }
}

// ---------------------------------------------------------------------------
// bf16 MFMA GEMM core: 64x64 out tile, K=384, BK=64, synchronous u8 staging
// with VGPR prefetch of the next K-chunk during compute. Padded LDS [64][72].
static __device__ __forceinline__ void gemm_core(
    const ushort* __restrict__ A, const ushort* __restrict__ B,
    ushort (* __restrict__ As)[72], ushort (* __restrict__ Bs)[72],
    int t, int w, int quad, int l15, f32x4 acc[4]) {
  const int g = t & 7;
  u8 ra[2], rb[2];
#pragma unroll
  for (int it = 0; it < 2; ++it) {
    const int r = it * 32 + (t >> 3);
    ra[it] = *(const u8*)&A[r * C_DIM + g * 8];
    rb[it] = *(const u8*)&B[r * C_DIM + g * 8];
  }
#pragma unroll 1
  for (int kt = 0; kt < 6; ++kt) {
    __syncthreads();                         // previous chunk's readers done
#pragma unroll
    for (int it = 0; it < 2; ++it) {
      const int r = it * 32 + (t >> 3);
      *(u8*)&As[r][g * 8] = ra[it];
      *(u8*)&Bs[r][g * 8] = rb[it];
    }
    __syncthreads();
    if (kt < 5) {
      const int k0 = (kt + 1) * 64;
#pragma unroll
      for (int it = 0; it < 2; ++it) {
        const int r = it * 32 + (t >> 3);
        ra[it] = *(const u8*)&A[r * C_DIM + k0 + g * 8];
        rb[it] = *(const u8*)&B[r * C_DIM + k0 + g * 8];
      }
    }
    const bh8 b0 = *(const bh8*)&Bs[w * 16 + l15][quad * 8];
    const bh8 b1 = *(const bh8*)&Bs[w * 16 + l15][32 + quad * 8];
#pragma unroll
    for (int mb = 0; mb < 4; ++mb) {
      const bh8 a0 = *(const bh8*)&As[mb * 16 + l15][quad * 8];
      const bh8 a1 = *(const bh8*)&As[mb * 16 + l15][32 + quad * 8];
      acc[mb] = __builtin_amdgcn_mfma_f32_16x16x32_bf16(a0, b0, acc[mb], 0, 0, 0);
      acc[mb] = __builtin_amdgcn_mfma_f32_16x16x32_bf16(a1, b1, acc[mb], 0, 0, 0);
    }
  }
}

// fused Q/K/V projection. y = which*6 + h. K epilogue scatters compacted
// rows via inv[] (row-major Kc); V epilogue writes transposed Vt directly.
__global__ __launch_bounds__(256) void gemm3_kernel(
    const ushort* __restrict__ Aq, const ushort* __restrict__ Ak,
    const ushort* __restrict__ Av, const ushort* __restrict__ Wb,
    const int* __restrict__ inv, ushort* __restrict__ Qh,
    ushort* __restrict__ Kc, ushort* __restrict__ Vt) {
  __shared__ ushort As[64][72], Bs[64][72];
  const int t = threadIdx.x, w = t >> 6, lane = t & 63;
  const int quad = lane >> 4, l15 = lane & 15;
  const int m0 = blockIdx.x * 64;
  const int which = blockIdx.y / 6, h = blockIdx.y % 6;
  const ushort* A = (which == 0 ? Aq : which == 1 ? Ak : Av) + (size_t)m0 * C_DIM;
  const ushort* B = Wb + (size_t)which * 147456 + (size_t)h * 64 * C_DIM;
  f32x4 acc[4];
#pragma unroll
  for (int i = 0; i < 4; ++i) acc[i] = (f32x4){0.f, 0.f, 0.f, 0.f};
  gemm_core(A, B, As, Bs, t, w, quad, l15, acc);
  const int n = w * 16 + l15;
  if (which == 0) {
#pragma unroll
    for (int mb = 0; mb < 4; ++mb)
#pragma unroll
      for (int r = 0; r < 4; ++r) {
        const int m = m0 + mb * 16 + quad * 4 + r;
        if (m < N_TOK) Qh[((size_t)h * N_TOK + m) * 64 + n] = f2bf(acc[mb][r]);
      }
  } else if (which == 1) {
#pragma unroll
    for (int mb = 0; mb < 4; ++mb)
#pragma unroll
      for (int r = 0; r < 4; ++r) {
        const int m = m0 + mb * 16 + quad * 4 + r;
        if (m < NK_TOK) {
          const int slot = inv[m];
          if (slot >= 0) Kc[((size_t)h * NKPAD + slot) * 64 + n] = f2bf(acc[mb][r]);
        }
      }
  } else {
    // V: write transposed layout [h][d=n][slot] directly (fused vtrans)
#pragma unroll
    for (int mb = 0; mb < 4; ++mb)
#pragma unroll
      for (int r = 0; r < 4; ++r) {
        const int m = m0 + mb * 16 + quad * 4 + r;
        if (m < NK_TOK) {
          const int slot = inv[m];
          if (slot >= 0) Vt[((size_t)h * 64 + n) * NKPAD + slot] = f2bf(acc[mb][r]);
        }
      }
  }
}

// output projection: fp32 out + bias
__global__ __launch_bounds__(256) void gemm_out_kernel(
    const ushort* __restrict__ Am, const ushort* __restrict__ Wpb,
    const float* __restrict__ bp, float* __restrict__ out) {
  __shared__ ushort As[64][72], Bs[64][72];
  const int t = threadIdx.x, w = t >> 6, lane = t & 63;
  const int quad = lane >> 4, l15 = lane & 15;
  const int m0 = blockIdx.x * 64;
  const int h = blockIdx.y;
  f32x4 acc[4];
#pragma unroll
  for (int i = 0; i < 4; ++i) acc[i] = (f32x4){0.f, 0.f, 0.f, 0.f};
  gemm_core(Am + (size_t)m0 * C_DIM, Wpb + (size_t)h * 64 * C_DIM,
            As, Bs, t, w, quad, l15, acc);
  const int n = w * 16 + l15;
  const float bb = bp[h * 64 + n];
#pragma unroll
  for (int mb = 0; mb < 4; ++mb)
#pragma unroll
    for (int r = 0; r < 4; ++r) {
      const int m = m0 + mb * 16 + quad * 4 + r;
      if (m < N_TOK) out[(size_t)m * C_DIM + h * 64 + n] = acc[mb][r] + bb;
    }
}

// ---------------------------------------------------------------------------
// MFMA flash attention: 256 q per block (4 q-frags/wave). The Ks/Vs fragment
// reads are per-wave fixed cost, so 4 q-frags amortize them over 2x the
// MFMAs vs the 128-q version (LDS bytes/FLOP 0.64x, barriers/FLOP halved).
// LDS-staged K/V with VGPR prefetch via loop-carried pointers; exp2-domain
// softmax; v_cvt_pk_bf16_f32 P-packing. grid (17 q-tiles, 6 heads, 6 slices).
__global__ __launch_bounds__(256) void attn_kernel(
    const ushort* __restrict__ Qh, const ushort* __restrict__ Kc,
    const ushort* __restrict__ Vt, const int* __restrict__ nkp,
    ushort* __restrict__ Opart, float* __restrict__ Lpart) {
  __shared__ ushort Ks[64][72];      // [slot][d]
  __shared__ ushort Vs[64][72];      // [d][slot]
  __shared__ ushort Ps[4][64][72];   // per-wave P^T staging, 4 q-frags
  const int t = threadIdx.x, w = t >> 6, lane = t & 63;
  const int quad = lane >> 4, l15 = lane & 15;
  const int h = blockIdx.y, slice = blockIdx.z;
  const int q0 = blockIdx.x * 256;
  const int nk = *nkp, nchunk = (nk + 63) >> 6;
  const int g = t & 7;

  bh8 qf[4][2];
#pragma unroll
  for (int qa = 0; qa < 4; ++qa) {
    int qr = q0 + w * 64 + qa * 16 + l15;
    if (qr > N_TOK - 1) qr = N_TOK - 1;      // clamp (stores guarded)
    const ushort* qp = Qh + ((size_t)h * N_TOK + qr) * 64 + quad * 8;
    qf[qa][0] = *(const bh8*)qp;
    qf[qa][1] = *(const bh8*)(qp + 32);
  }
  f32x4 oacc[4][4];
#pragma unroll
  for (int qa = 0; qa < 4; ++qa)
#pragma unroll
    for (int i = 0; i < 4; ++i) oacc[qa][i] = (f32x4){0.f, 0.f, 0.f, 0.f};
  float l_r[4] = {0.f, 0.f, 0.f, 0.f};

  const ushort* kb = Kc + (size_t)h * NKPAD * 64;
  const ushort* vb = Vt + (size_t)h * 64 * NKPAD;

  // loop-carried staging pointers (strength-reduced addressing)
  const ushort* kstage = kb + ((size_t)slice * 64 + (t >> 3)) * 64 + g * 8;
  const ushort* vstage = vb + (size_t)(t >> 3) * NKPAD + slice * 64 + g * 8;

  u8 rk[2], rv[2];
  if (slice < nchunk) {
    rk[0] = *(const u8*)kstage;
    rk[1] = *(const u8*)(kstage + 32 * 64);
    rv[0] = *(const u8*)vstage;
    rv[1] = *(const u8*)(vstage + (size_t)32 * NKPAD);
  }
#pragma unroll 1
  for (int kc = slice; kc < nchunk; kc += NSLICE) {
    __syncthreads();                          // previous chunk's readers done
    {
      const int r = t >> 3;
      *(u8*)&Ks[r][g * 8] = rk[0];
      *(u8*)&Ks[32 + r][g * 8] = rk[1];
      *(u8*)&Vs[r][g * 8] = rv[0];
      *(u8*)&Vs[32 + r][g * 8] = rv[1];
    }
    __syncthreads();
    if (kc + NSLICE < nchunk) {               // prefetch next chunk into VGPRs
      kstage += NSLICE * 64 * 64;
      vstage += NSLICE * 64;
      rk[0] = *(const u8*)kstage;
      rk[1] = *(const u8*)(kstage + 32 * 64);
      rv[0] = *(const u8*)vstage;
      rv[1] = *(const u8*)(vstage + (size_t)32 * NKPAD);
    }
    float csum[4] = {0.f, 0.f, 0.f, 0.f};
#pragma unroll
    for (int f = 0; f < 4; ++f) {
      const bh8 a0 = *(const bh8*)&Ks[f * 16 + l15][quad * 8];
      const bh8 a1 = *(const bh8*)&Ks[f * 16 + l15][32 + quad * 8];
      const int keyb = kc * 64 + f * 16 + quad * 4;
#pragma unroll
      for (int qa = 0; qa < 4; ++qa) {
        f32x4 s4 = {0.f, 0.f, 0.f, 0.f};
        s4 = __builtin_amdgcn_mfma_f32_16x16x32_bf16(a0, qf[qa][0], s4, 0, 0, 0);
        s4 = __builtin_amdgcn_mfma_f32_16x16x32_bf16(a1, qf[qa][1], s4, 0, 0, 0);
        const float p0 = (keyb + 0 < nk) ? __builtin_amdgcn_exp2f(s4[0]) : 0.f;
        const float p1 = (keyb + 1 < nk) ? __builtin_amdgcn_exp2f(s4[1]) : 0.f;
        const float p2 = (keyb + 2 < nk) ? __builtin_amdgcn_exp2f(s4[2]) : 0.f;
        const float p3 = (keyb + 3 < nk) ? __builtin_amdgcn_exp2f(s4[3]) : 0.f;
        csum[qa] += (p0 + p1) + (p2 + p3);
        unsigned int lo, hi;
        asm("v_cvt_pk_bf16_f32 %0, %1, %2" : "=v"(lo) : "v"(p0), "v"(p1));
        asm("v_cvt_pk_bf16_f32 %0, %1, %2" : "=v"(hi) : "v"(p2), "v"(p3));
        uint2 pk;
        pk.x = lo; pk.y = hi;
        *(uint2*)&Ps[w][qa * 16 + l15][f * 16 + quad * 4] = pk;
      }
    }
#pragma unroll
    for (int qa = 0; qa < 4; ++qa) {
      csum[qa] += __shfl_xor(csum[qa], 16);
      csum[qa] += __shfl_xor(csum[qa], 32);
      l_r[qa] += csum[qa];
    }

    bh8 pa0[4], pa1[4];
#pragma unroll
    for (int qa = 0; qa < 4; ++qa) {
      pa0[qa] = *(const bh8*)&Ps[w][qa * 16 + l15][quad * 8];
      pa1[qa] = *(const bh8*)&Ps[w][qa * 16 + l15][32 + quad * 8];
    }
#pragma unroll
    for (int db = 0; db < 4; ++db) {
      const bh8 b0 = *(const bh8*)&Vs[db * 16 + l15][quad * 8];
      const bh8 b1 = *(const bh8*)&Vs[db * 16 + l15][32 + quad * 8];
#pragma unroll
      for (int qa = 0; qa < 4; ++qa) {
        oacc[qa][db] = __builtin_amdgcn_mfma_f32_16x16x32_bf16(pa0[qa], b0, oacc[qa][db], 0, 0, 0);
        oacc[qa][db] = __builtin_amdgcn_mfma_f32_16x16x32_bf16(pa1[qa], b1, oacc[qa][db], 0, 0, 0);
      }
    }
  }

  const int sh = slice * 6 + h;
#pragma unroll
  for (int qa = 0; qa < 4; ++qa) {
    const int qg = q0 + w * 64 + qa * 16;
#pragma unroll
    for (int db = 0; db < 4; ++db)
#pragma unroll
      for (int r = 0; r < 4; ++r) {
        const int q = qg + quad * 4 + r;
        if (q < N_TOK)
          Opart[((size_t)sh * NKPAD + q) * 64 + db * 16 + l15] = f2bf(oacc[qa][db][r]);
      }
    if (quad == 0) {
      const int q = qg + l15;
      if (q < N_TOK) Lpart[sh * NKPAD + q] = l_r[qa];
    }
  }
}

// merge NSLICE key-slice partials -> bf16 Am [4160][384]
__global__ __launch_bounds__(256) void merge_kernel(const ushort* __restrict__ Opart,
                                                    const float* __restrict__ Lpart,
                                                    ushort* __restrict__ Am) {
  const int idx = blockIdx.x * 256 + threadIdx.x;     // u8 chunk index
  if (idx >= N_TOK * 48) return;
  const int q = idx / 48, c = (idx % 48) * 8;
  const int h = c >> 6, d = c & 63;
  float l = 0.f;
#pragma unroll
  for (int s = 0; s < NSLICE; ++s) l += Lpart[(s * 6 + h) * NKPAD + q];
  const float inv = 1.f / l;
  float o[8] = {0.f, 0.f, 0.f, 0.f, 0.f, 0.f, 0.f, 0.f};
#pragma unroll
  for (int s = 0; s < NSLICE; ++s) {
    const u8 v = *(const u8*)&Opart[((size_t)(s * 6 + h) * NKPAD + q) * 64 + d];
#pragma unroll
    for (int j = 0; j < 8; ++j) o[j] += bf2f(v[j]);
  }
  u8 r;
#pragma unroll
  for (int j = 0; j < 8; ++j) r[j] = f2bf(o[j] * inv);
  *(u8*)&Am[(size_t)q * C_DIM + c] = r;
}

// ---------------------------------------------------------------------------
extern "C" void kernel_launch(void* const* d_in, const int* in_sizes, int n_in,
                              void* d_out, int out_size, void* d_ws, size_t ws_size,
                              hipStream_t stream) {
  const float* x          = (const float*)d_in[0];
  const float* pos        = (const float*)d_in[1];
  const float* mask       = (const float*)d_in[2];
  const float* mask_block = (const float*)d_in[3];
  const float* Wq         = (const float*)d_in[4];
  const float* Wk         = (const float*)d_in[5];
  const float* Wv         = (const float*)d_in[6];
  const float* Wp         = (const float*)d_in[7];
  const float* bp         = (const float*)d_in[8];
  float* out = (float*)d_out;
  char* wsb = (char*)d_ws;

  float*  pooled_part = (float*)wsb;                // [128][384]
  float*  cnt_part    = (float*)(wsb + 196608);     // [128]
  int*    nk          = (int*)(wsb + 197120);
  int*    inv         = (int*)(wsb + 197632);       // [4099]
  ushort* Aq          = (ushort*)(wsb + 215296);    // [4160][384]
  ushort* Ak          = (ushort*)(wsb + 3410176);   // [4160][384]
  ushort* Av          = (ushort*)(wsb + 6605056);   // [4160][384]
  ushort* Wb          = (ushort*)(wsb + 9799936);   // [4][384][384]
  ushort* Qh          = (ushort*)(wsb + 10979584);  // [6][4098][64]
  ushort* Kc          = (ushort*)(wsb + 14126848);  // [6][4160][64]
  ushort* Vt          = (ushort*)(wsb + 17321728);  // [6][64][4160]
  ushort* Am          = (ushort*)(wsb + 24011008);  // [4160][384]
  ushort* Op          = (ushort*)(wsb + 27205888);  // [36][4160][64]
  float*  Lp          = (float*)(wsb + 46375168);   // [36][4160]

  pool_kernel<<<dim3(128), dim3(384), 0, stream>>>(x, mask, pooled_part, cnt_part);
  prep_kernel<<<dim3(293), dim3(256), 0, stream>>>(x, pos, pooled_part, cnt_part,
                                                   Wq, Wk, Wv, Wp, mask, mask_block,
                                                   Aq, Ak, Av, Wb, nk, inv);
  gemm3_kernel<<<dim3(65, 18), 256, 0, stream>>>(Aq, Ak, Av, Wb, inv, Qh, Kc, Vt);
  attn_kernel<<<dim3(17, 6, NSLICE), 256, 0, stream>>>(Qh, Kc, Vt, nk, Op, Lp);
  merge_kernel<<<dim3(769), 256, 0, stream>>>(Op, Lp, Am);
  gemm_out_kernel<<<dim3(65, 6), 256, 0, stream>>>(Am, Wb + 3 * 147456, bp, out);
}

// Round 6
// 154.778 us; speedup vs baseline: 1.0359x; 1.0359x over previous
//
#include <hip/hip_runtime.h>
#include <math.h>

#define N_TOK 4098
#define NK_TOK 4099
#define C_DIM 384
#define NKPAD 4160
#define NSLICE 3
// HEADS = 6, HD = 64

typedef short  bh8 __attribute__((ext_vector_type(8)));   // 8 bf16 (4 VGPRs)
typedef float  f32x4 __attribute__((ext_vector_type(4)));
typedef unsigned short ushort;
typedef ushort u4 __attribute__((ext_vector_type(4)));
typedef ushort u8 __attribute__((ext_vector_type(8)));

static __device__ __forceinline__ ushort f2bf(float f) {
  unsigned int u = __float_as_uint(f);
  u = (u + 0x7FFF + ((u >> 16) & 1)) >> 16;   // RNE
  return (ushort)u;
}
static __device__ __forceinline__ float bf2f(ushort s) {
  return __uint_as_float(((unsigned int)s) << 16);
}

// Q pre-scale: D^-0.5 * log2(e); attention exp computed as exp2
#define QSCALE 0.18033688011112042f

// ---------------------------------------------------------------------------
// pool partials (no atomics, no memset needed)
__global__ __launch_bounds__(384) void pool_kernel(
    const float* __restrict__ x, const float* __restrict__ mask,
    float* __restrict__ pooled_part, float* __restrict__ cnt_part) {
  const int b = blockIdx.x, t = threadIdx.x;
  const int r0 = b * 32;
  float acc = 0.f;
  int lc = 0;
  for (int r = r0; r < r0 + 32; ++r)
    if (mask[r] < 0.5f) { acc += x[(size_t)(r + 1) * C_DIM + t]; ++lc; }
  pooled_part[b * C_DIM + t] = acc;
  if (t == 0) cnt_part[b] = (float)lc;
}

// ---------------------------------------------------------------------------
// prep: blocks 0..259 build bf16 A-matrices (16 rows each); block 256 first
// reduces pool partials -> back token (row 4098). blocks 260..291 convert W.
// block 292: single-block keep-compaction prefix scan -> inv[], nk.
__global__ __launch_bounds__(256) void prep_kernel(
    const float* __restrict__ x, const float* __restrict__ pos,
    const float* __restrict__ pooled_part, const float* __restrict__ cnt_part,
    const float* __restrict__ Wq, const float* __restrict__ Wk,
    const float* __restrict__ Wv, const float* __restrict__ Wp,
    const float* __restrict__ mask, const float* __restrict__ mask_block,
    ushort* __restrict__ Aq, ushort* __restrict__ Ak, ushort* __restrict__ Av,
    ushort* __restrict__ Wb, int* __restrict__ nk, int* __restrict__ inv) {
  const int b = blockIdx.x, t = threadIdx.x;
  if (b < 260) {
    __shared__ float sback[C_DIM];
    if (b == 256) {                         // back token for row 4098
      float cs = 0.f;
      for (int i = (t & 63); i < 128; i += 64) cs += cnt_part[i];
#pragma unroll
      for (int d = 1; d < 64; d <<= 1) cs += __shfl_xor(cs, d);
      const float ic = 1.f / (cs + 1e-10f);
      for (int c = t; c < C_DIM; c += 256) {
        float s = 0.f;
        for (int p = 0; p < 128; ++p) s += pooled_part[p * C_DIM + c];
        sback[c] = s * ic;
      }
      __syncthreads();
    }
    const int r0 = b * 16;
#pragma unroll
    for (int i = 0; i < 6; ++i) {
      const int idx = i * 1024 + t * 4;
      const int row = r0 + idx / C_DIM, col = idx % C_DIM;
      if (row >= NK_TOK) continue;
      const float4 pv = *(const float4*)&pos[(size_t)row * C_DIM + col];
      float4 xv;
      if (row == NK_TOK - 1)
        xv = make_float4(sback[col], sback[col + 1], sback[col + 2], sback[col + 3]);
      else
        xv = *(const float4*)&x[(size_t)row * C_DIM + col];
      if (row < N_TOK) {
        u4 q4 = {f2bf((xv.x + pv.x) * QSCALE), f2bf((xv.y + pv.y) * QSCALE),
                 f2bf((xv.z + pv.z) * QSCALE), f2bf((xv.w + pv.w) * QSCALE)};
        *(u4*)&Aq[(size_t)row * C_DIM + col] = q4;
      }
      u4 k4 = {f2bf(xv.x + pv.x), f2bf(xv.y + pv.y),
               f2bf(xv.z + pv.z), f2bf(xv.w + pv.w)};
      *(u4*)&Ak[(size_t)row * C_DIM + col] = k4;
      u4 v4 = {f2bf(xv.x), f2bf(xv.y), f2bf(xv.z), f2bf(xv.w)};
      *(u4*)&Av[(size_t)row * C_DIM + col] = v4;
    }
  } else if (b < 292) {
    const int wi = b - 260;                  // 0..31; 8 blocks per weight
    const float* src = (wi < 8) ? Wq : (wi < 16) ? Wk : (wi < 24) ? Wv : Wp;
    const int base = (wi >> 3) * 147456 + (wi & 7) * 18432;
#pragma unroll 2
    for (int i = 0; i < 18; ++i) {
      const int g = base + i * 1024 + t * 4;
      const float4 v = *(const float4*)&src[(wi & 7) * 18432 + i * 1024 + t * 4];
      u4 o = {f2bf(v.x), f2bf(v.y), f2bf(v.z), f2bf(v.w)};
      *(u4*)&Wb[g] = o;
    }
  } else {
    // keep-compaction: 256 threads x 17 elements, block prefix scan
    __shared__ int scnt[256];
    const int j0 = t * 17;
    unsigned int bits = 0;
    int c = 0;
#pragma unroll 1
    for (int u = 0; u < 17; ++u) {
      const int j = j0 + u;
      bool keep = false;
      if (j < NK_TOK)
        keep = (j >= 1 && j <= N_TOK - 2) ? (mask[j - 1] >= 0.5f)
                                          : (mask_block[j] >= 0.5f);
      if (keep) { bits |= 1u << u; ++c; }
    }
    scnt[t] = c;
    __syncthreads();
    for (int d = 1; d < 256; d <<= 1) {
      const int v = scnt[t];
      const int add = (t >= d) ? scnt[t - d] : 0;
      __syncthreads();
      scnt[t] = v + add;
      __syncthreads();
    }
    int base = scnt[t] - c;                  // exclusive prefix
    if (t == 255) *nk = scnt[255];
#pragma unroll 1
    for (int u = 0; u < 17; ++u) {
      const int j = j0 + u;
      if (j < NK_TOK) inv[j] = ((bits >> u) & 1) ? base++ : -1;
    }
  }
}

// ---------------------------------------------------------------------------
// bf16 MFMA GEMM core: 64x64 out tile, K=384, BK=64, DOUBLE-BUFFERED LDS
// (one barrier per K-chunk instead of two): iter kt computes from buf[kt&1]
// while writing tile kt+1 into buf[(kt+1)&1]. The barrier at the top of
// iter kt guarantees all waves finished iter kt-1 (incl. reads of
// buf[(kt+1)&1]), so the overwrite is race-free. Padded LDS [64][72].
static __device__ __forceinline__ void gemm_core(
    const ushort* __restrict__ A, const ushort* __restrict__ B,
    ushort (* __restrict__ As)[64][72], ushort (* __restrict__ Bs)[64][72],
    int t, int w, int quad, int l15, f32x4 acc[4]) {
  const int g = t & 7;
  const int r = t >> 3;                      // 0..31
  u8 ra[2], rb[2];
#pragma unroll
  for (int it = 0; it < 2; ++it) {
    ra[it] = *(const u8*)&A[(it * 32 + r) * C_DIM + g * 8];
    rb[it] = *(const u8*)&B[(it * 32 + r) * C_DIM + g * 8];
  }
#pragma unroll
  for (int it = 0; it < 2; ++it) {           // tile 0 -> buf 0 (pre-barrier)
    *(u8*)&As[0][it * 32 + r][g * 8] = ra[it];
    *(u8*)&Bs[0][it * 32 + r][g * 8] = rb[it];
  }
#pragma unroll 1
  for (int kt = 0; kt < 6; ++kt) {
    if (kt < 5) {                            // issue next-tile global loads
      const int k0 = (kt + 1) * 64;
#pragma unroll
      for (int it = 0; it < 2; ++it) {
        ra[it] = *(const u8*)&A[(it * 32 + r) * C_DIM + k0 + g * 8];
        rb[it] = *(const u8*)&B[(it * 32 + r) * C_DIM + k0 + g * 8];
      }
    }
    __syncthreads();                         // buf[kt&1] ready; kt-1 reads done
    const int cb = kt & 1;
    const bh8 b0 = *(const bh8*)&Bs[cb][w * 16 + l15][quad * 8];
    const bh8 b1 = *(const bh8*)&Bs[cb][w * 16 + l15][32 + quad * 8];
#pragma unroll
    for (int mb = 0; mb < 4; ++mb) {
      const bh8 a0 = *(const bh8*)&As[cb][mb * 16 + l15][quad * 8];
      const bh8 a1 = *(const bh8*)&As[cb][mb * 16 + l15][32 + quad * 8];
      acc[mb] = __builtin_amdgcn_mfma_f32_16x16x32_bf16(a0, b0, acc[mb], 0, 0, 0);
      acc[mb] = __builtin_amdgcn_mfma_f32_16x16x32_bf16(a1, b1, acc[mb], 0, 0, 0);
    }
    if (kt < 5) {                            // stage tile kt+1 into other buf
#pragma unroll
      for (int it = 0; it < 2; ++it) {
        *(u8*)&As[cb ^ 1][it * 32 + r][g * 8] = ra[it];
        *(u8*)&Bs[cb ^ 1][it * 32 + r][g * 8] = rb[it];
      }
    }
  }
}

// fused Q/K/V projection. y = which*6 + h. K epilogue scatters compacted
// rows via inv[] (row-major Kc); V epilogue writes transposed Vt directly.
__global__ __launch_bounds__(256) void gemm3_kernel(
    const ushort* __restrict__ Aq, const ushort* __restrict__ Ak,
    const ushort* __restrict__ Av, const ushort* __restrict__ Wb,
    const int* __restrict__ inv, ushort* __restrict__ Qh,
    ushort* __restrict__ Kc, ushort* __restrict__ Vt) {
  __shared__ ushort As[2][64][72], Bs[2][64][72];
  const int t = threadIdx.x, w = t >> 6, lane = t & 63;
  const int quad = lane >> 4, l15 = lane & 15;
  const int m0 = blockIdx.x * 64;
  const int which = blockIdx.y / 6, h = blockIdx.y % 6;
  const ushort* A = (which == 0 ? Aq : which == 1 ? Ak : Av) + (size_t)m0 * C_DIM;
  const ushort* B = Wb + (size_t)which * 147456 + (size_t)h * 64 * C_DIM;
  f32x4 acc[4];
#pragma unroll
  for (int i = 0; i < 4; ++i) acc[i] = (f32x4){0.f, 0.f, 0.f, 0.f};
  gemm_core(A, B, As, Bs, t, w, quad, l15, acc);
  const int n = w * 16 + l15;
  if (which == 0) {
#pragma unroll
    for (int mb = 0; mb < 4; ++mb)
#pragma unroll
      for (int r = 0; r < 4; ++r) {
        const int m = m0 + mb * 16 + quad * 4 + r;
        if (m < N_TOK) Qh[((size_t)h * N_TOK + m) * 64 + n] = f2bf(acc[mb][r]);
      }
  } else if (which == 1) {
#pragma unroll
    for (int mb = 0; mb < 4; ++mb)
#pragma unroll
      for (int r = 0; r < 4; ++r) {
        const int m = m0 + mb * 16 + quad * 4 + r;
        if (m < NK_TOK) {
          const int slot = inv[m];
          if (slot >= 0) Kc[((size_t)h * NKPAD + slot) * 64 + n] = f2bf(acc[mb][r]);
        }
      }
  } else {
    // V: write transposed layout [h][d=n][slot] directly (fused vtrans)
#pragma unroll
    for (int mb = 0; mb < 4; ++mb)
#pragma unroll
      for (int r = 0; r < 4; ++r) {
        const int m = m0 + mb * 16 + quad * 4 + r;
        if (m < NK_TOK) {
          const int slot = inv[m];
          if (slot >= 0) Vt[((size_t)h * 64 + n) * NKPAD + slot] = f2bf(acc[mb][r]);
        }
      }
  }
}

// output projection: fp32 out + bias
__global__ __launch_bounds__(256) void gemm_out_kernel(
    const ushort* __restrict__ Am, const ushort* __restrict__ Wpb,
    const float* __restrict__ bp, float* __restrict__ out) {
  __shared__ ushort As[2][64][72], Bs[2][64][72];
  const int t = threadIdx.x, w = t >> 6, lane = t & 63;
  const int quad = lane >> 4, l15 = lane & 15;
  const int m0 = blockIdx.x * 64;
  const int h = blockIdx.y;
  f32x4 acc[4];
#pragma unroll
  for (int i = 0; i < 4; ++i) acc[i] = (f32x4){0.f, 0.f, 0.f, 0.f};
  gemm_core(Am + (size_t)m0 * C_DIM, Wpb + (size_t)h * 64 * C_DIM,
            As, Bs, t, w, quad, l15, acc);
  const int n = w * 16 + l15;
  const float bb = bp[h * 64 + n];
#pragma unroll
  for (int mb = 0; mb < 4; ++mb)
#pragma unroll
    for (int r = 0; r < 4; ++r) {
      const int m = m0 + mb * 16 + quad * 4 + r;
      if (m < N_TOK) out[(size_t)m * C_DIM + h * 64 + n] = acc[mb][r] + bb;
    }
}

// ---------------------------------------------------------------------------
// MFMA flash attention: 128 q per block (2 q-frags/wave); LDS-staged K/V
// with VGPR prefetch via loop-carried pointers; exp2-domain softmax;
// v_cvt_pk_bf16_f32 P-packing. NSLICE=3 key slices (nk ~ 2051 -> ~11 chunks
// per block; 594 blocks all co-resident at 4 blocks/CU; halves the
// Opart/merge partial traffic vs NSLICE=6).
__global__ __launch_bounds__(256) void attn_kernel(
    const ushort* __restrict__ Qh, const ushort* __restrict__ Kc,
    const ushort* __restrict__ Vt, const int* __restrict__ nkp,
    ushort* __restrict__ Opart, float* __restrict__ Lpart) {
  __shared__ ushort Ks[64][72];      // [slot][d]
  __shared__ ushort Vs[64][72];      // [d][slot]
  __shared__ ushort Ps[4][32][72];   // per-wave P^T staging, 2 q-frags
  const int t = threadIdx.x, w = t >> 6, lane = t & 63;
  const int quad = lane >> 4, l15 = lane & 15;
  const int h = blockIdx.y, slice = blockIdx.z;
  const int q0 = blockIdx.x * 128;
  const int nk = *nkp, nchunk = (nk + 63) >> 6;
  const int g = t & 7;

  bh8 qf[2][2];
#pragma unroll
  for (int qa = 0; qa < 2; ++qa) {
    int qr = q0 + w * 32 + qa * 16 + l15;
    if (qr > N_TOK - 1) qr = N_TOK - 1;      // clamp (stores guarded)
    const ushort* qp = Qh + ((size_t)h * N_TOK + qr) * 64 + quad * 8;
    qf[qa][0] = *(const bh8*)qp;
    qf[qa][1] = *(const bh8*)(qp + 32);
  }
  f32x4 oacc[2][4];
#pragma unroll
  for (int qa = 0; qa < 2; ++qa)
#pragma unroll
    for (int i = 0; i < 4; ++i) oacc[qa][i] = (f32x4){0.f, 0.f, 0.f, 0.f};
  float l_r[2] = {0.f, 0.f};

  const ushort* kb = Kc + (size_t)h * NKPAD * 64;
  const ushort* vb = Vt + (size_t)h * 64 * NKPAD;

  // loop-carried staging pointers (strength-reduced addressing)
  const ushort* kstage = kb + ((size_t)slice * 64 + (t >> 3)) * 64 + g * 8;
  const ushort* vstage = vb + (size_t)(t >> 3) * NKPAD + slice * 64 + g * 8;

  u8 rk[2], rv[2];
  if (slice < nchunk) {
    rk[0] = *(const u8*)kstage;
    rk[1] = *(const u8*)(kstage + 32 * 64);
    rv[0] = *(const u8*)vstage;
    rv[1] = *(const u8*)(vstage + (size_t)32 * NKPAD);
  }
#pragma unroll 1
  for (int kc = slice; kc < nchunk; kc += NSLICE) {
    __syncthreads();                          // previous chunk's readers done
    {
      const int r = t >> 3;
      *(u8*)&Ks[r][g * 8] = rk[0];
      *(u8*)&Ks[32 + r][g * 8] = rk[1];
      *(u8*)&Vs[r][g * 8] = rv[0];
      *(u8*)&Vs[32 + r][g * 8] = rv[1];
    }
    __syncthreads();
    if (kc + NSLICE < nchunk) {               // prefetch next chunk into VGPRs
      kstage += NSLICE * 64 * 64;
      vstage += NSLICE * 64;
      rk[0] = *(const u8*)kstage;
      rk[1] = *(const u8*)(kstage + 32 * 64);
      rv[0] = *(const u8*)vstage;
      rv[1] = *(const u8*)(vstage + (size_t)32 * NKPAD);
    }
    float csum[2] = {0.f, 0.f};
#pragma unroll
    for (int f = 0; f < 4; ++f) {
      const bh8 a0 = *(const bh8*)&Ks[f * 16 + l15][quad * 8];
      const bh8 a1 = *(const bh8*)&Ks[f * 16 + l15][32 + quad * 8];
      f32x4 s4[2];
#pragma unroll
      for (int qa = 0; qa < 2; ++qa) {
        s4[qa] = (f32x4){0.f, 0.f, 0.f, 0.f};
        s4[qa] = __builtin_amdgcn_mfma_f32_16x16x32_bf16(a0, qf[qa][0], s4[qa], 0, 0, 0);
        s4[qa] = __builtin_amdgcn_mfma_f32_16x16x32_bf16(a1, qf[qa][1], s4[qa], 0, 0, 0);
      }
      const int keyb = kc * 64 + f * 16 + quad * 4;
#pragma unroll
      for (int qa = 0; qa < 2; ++qa) {
        const float p0 = (keyb + 0 < nk) ? __builtin_amdgcn_exp2f(s4[qa][0]) : 0.f;
        const float p1 = (keyb + 1 < nk) ? __builtin_amdgcn_exp2f(s4[qa][1]) : 0.f;
        const float p2 = (keyb + 2 < nk) ? __builtin_amdgcn_exp2f(s4[qa][2]) : 0.f;
        const float p3 = (keyb + 3 < nk) ? __builtin_amdgcn_exp2f(s4[qa][3]) : 0.f;
        csum[qa] += (p0 + p1) + (p2 + p3);
        unsigned int lo, hi;
        asm("v_cvt_pk_bf16_f32 %0, %1, %2" : "=v"(lo) : "v"(p0), "v"(p1));
        asm("v_cvt_pk_bf16_f32 %0, %1, %2" : "=v"(hi) : "v"(p2), "v"(p3));
        uint2 pk;
        pk.x = lo; pk.y = hi;
        *(uint2*)&Ps[w][qa * 16 + l15][f * 16 + quad * 4] = pk;
      }
    }
#pragma unroll
    for (int qa = 0; qa < 2; ++qa) {
      csum[qa] += __shfl_xor(csum[qa], 16);
      csum[qa] += __shfl_xor(csum[qa], 32);
      l_r[qa] += csum[qa];
    }

    bh8 pa[2][2];
#pragma unroll
    for (int qa = 0; qa < 2; ++qa) {
      pa[qa][0] = *(const bh8*)&Ps[w][qa * 16 + l15][quad * 8];
      pa[qa][1] = *(const bh8*)&Ps[w][qa * 16 + l15][32 + quad * 8];
    }
#pragma unroll
    for (int db = 0; db < 4; ++db) {
      const bh8 b0 = *(const bh8*)&Vs[db * 16 + l15][quad * 8];
      const bh8 b1 = *(const bh8*)&Vs[db * 16 + l15][32 + quad * 8];
#pragma unroll
      for (int qa = 0; qa < 2; ++qa) {
        oacc[qa][db] = __builtin_amdgcn_mfma_f32_16x16x32_bf16(pa[qa][0], b0, oacc[qa][db], 0, 0, 0);
        oacc[qa][db] = __builtin_amdgcn_mfma_f32_16x16x32_bf16(pa[qa][1], b1, oacc[qa][db], 0, 0, 0);
      }
    }
  }

  const int sh = slice * 6 + h;
#pragma unroll
  for (int qa = 0; qa < 2; ++qa) {
    const int qg = q0 + w * 32 + qa * 16;
#pragma unroll
    for (int db = 0; db < 4; ++db)
#pragma unroll
      for (int r = 0; r < 4; ++r) {
        const int q = qg + quad * 4 + r;
        if (q < N_TOK)
          Opart[((size_t)sh * NKPAD + q) * 64 + db * 16 + l15] = f2bf(oacc[qa][db][r]);
      }
    if (quad == 0) {
      const int q = qg + l15;
      if (q < N_TOK) Lpart[sh * NKPAD + q] = l_r[qa];
    }
  }
}

// merge NSLICE key-slice partials -> bf16 Am [4160][384]
__global__ __launch_bounds__(256) void merge_kernel(const ushort* __restrict__ Opart,
                                                    const float* __restrict__ Lpart,
                                                    ushort* __restrict__ Am) {
  const int idx = blockIdx.x * 256 + threadIdx.x;     // u8 chunk index
  if (idx >= N_TOK * 48) return;
  const int q = idx / 48, c = (idx % 48) * 8;
  const int h = c >> 6, d = c & 63;
  float l = 0.f;
#pragma unroll
  for (int s = 0; s < NSLICE; ++s) l += Lpart[(s * 6 + h) * NKPAD + q];
  const float inv = 1.f / l;
  float o[8] = {0.f, 0.f, 0.f, 0.f, 0.f, 0.f, 0.f, 0.f};
#pragma unroll
  for (int s = 0; s < NSLICE; ++s) {
    const u8 v = *(const u8*)&Opart[((size_t)(s * 6 + h) * NKPAD + q) * 64 + d];
#pragma unroll
    for (int j = 0; j < 8; ++j) o[j] += bf2f(v[j]);
  }
  u8 r;
#pragma unroll
  for (int j = 0; j < 8; ++j) r[j] = f2bf(o[j] * inv);
  *(u8*)&Am[(size_t)q * C_DIM + c] = r;
}

// ---------------------------------------------------------------------------
extern "C" void kernel_launch(void* const* d_in, const int* in_sizes, int n_in,
                              void* d_out, int out_size, void* d_ws, size_t ws_size,
                              hipStream_t stream) {
  const float* x          = (const float*)d_in[0];
  const float* pos        = (const float*)d_in[1];
  const float* mask       = (const float*)d_in[2];
  const float* mask_block = (const float*)d_in[3];
  const float* Wq         = (const float*)d_in[4];
  const float* Wk         = (const float*)d_in[5];
  const float* Wv         = (const float*)d_in[6];
  const float* Wp         = (const float*)d_in[7];
  const float* bp         = (const float*)d_in[8];
  float* out = (float*)d_out;
  char* wsb = (char*)d_ws;

  float*  pooled_part = (float*)wsb;                // [128][384]
  float*  cnt_part    = (float*)(wsb + 196608);     // [128]
  int*    nk          = (int*)(wsb + 197120);
  int*    inv         = (int*)(wsb + 197632);       // [4099]
  ushort* Aq          = (ushort*)(wsb + 215296);    // [4160][384]
  ushort* Ak          = (ushort*)(wsb + 3410176);   // [4160][384]
  ushort* Av          = (ushort*)(wsb + 6605056);   // [4160][384]
  ushort* Wb          = (ushort*)(wsb + 9799936);   // [4][384][384]
  ushort* Qh          = (ushort*)(wsb + 10979584);  // [6][4098][64]
  ushort* Kc          = (ushort*)(wsb + 14126848);  // [6][4160][64]
  ushort* Vt          = (ushort*)(wsb + 17321728);  // [6][64][4160]
  ushort* Am          = (ushort*)(wsb + 24011008);  // [4160][384]
  ushort* Op          = (ushort*)(wsb + 27205888);  // [18][4160][64]
  float*  Lp          = (float*)(wsb + 46375168);   // [18][4160]

  pool_kernel<<<dim3(128), dim3(384), 0, stream>>>(x, mask, pooled_part, cnt_part);
  prep_kernel<<<dim3(293), dim3(256), 0, stream>>>(x, pos, pooled_part, cnt_part,
                                                   Wq, Wk, Wv, Wp, mask, mask_block,
                                                   Aq, Ak, Av, Wb, nk, inv);
  gemm3_kernel<<<dim3(65, 18), 256, 0, stream>>>(Aq, Ak, Av, Wb, inv, Qh, Kc, Vt);
  attn_kernel<<<dim3(33, 6, NSLICE), 256, 0, stream>>>(Qh, Kc, Vt, nk, Op, Lp);
  merge_kernel<<<dim3(769), 256, 0, stream>>>(Op, Lp, Am);
  gemm_out_kernel<<<dim3(65, 6), 256, 0, stream>>>(Am, Wb + 3 * 147456, bp, out);
}

// Round 7
// 154.578 us; speedup vs baseline: 1.0373x; 1.0013x over previous
//
#include <hip/hip_runtime.h>
#include <math.h>

#define N_TOK 4098
#define NK_TOK 4099
#define C_DIM 384
#define NKPAD 4160
#define NSLICE 6
// HEADS = 6, HD = 64

typedef short  bh8 __attribute__((ext_vector_type(8)));   // 8 bf16 (4 VGPRs)
typedef float  f32x4 __attribute__((ext_vector_type(4)));
typedef unsigned short ushort;
typedef ushort u4 __attribute__((ext_vector_type(4)));
typedef ushort u8 __attribute__((ext_vector_type(8)));

static __device__ __forceinline__ ushort f2bf(float f) {
  unsigned int u = __float_as_uint(f);
  u = (u + 0x7FFF + ((u >> 16) & 1)) >> 16;   // RNE
  return (ushort)u;
}
static __device__ __forceinline__ float bf2f(ushort s) {
  return __uint_as_float(((unsigned int)s) << 16);
}

// Q pre-scale: D^-0.5 * log2(e); attention exp computed as exp2
#define QSCALE 0.18033688011112042f

// ---------------------------------------------------------------------------
// pool partials (no atomics, no memset needed)
__global__ __launch_bounds__(384) void pool_kernel(
    const float* __restrict__ x, const float* __restrict__ mask,
    float* __restrict__ pooled_part, float* __restrict__ cnt_part) {
  const int b = blockIdx.x, t = threadIdx.x;
  const int r0 = b * 32;
  float acc = 0.f;
  int lc = 0;
  for (int r = r0; r < r0 + 32; ++r)
    if (mask[r] < 0.5f) { acc += x[(size_t)(r + 1) * C_DIM + t]; ++lc; }
  pooled_part[b * C_DIM + t] = acc;
  if (t == 0) cnt_part[b] = (float)lc;
}

// ---------------------------------------------------------------------------
// prep: blocks 0..259 build bf16 A-matrices (16 rows each); block 256 first
// reduces pool partials -> back token (row 4098). blocks 260..291 convert W.
// block 292: single-block keep-compaction prefix scan -> inv[], nk.
__global__ __launch_bounds__(256) void prep_kernel(
    const float* __restrict__ x, const float* __restrict__ pos,
    const float* __restrict__ pooled_part, const float* __restrict__ cnt_part,
    const float* __restrict__ Wq, const float* __restrict__ Wk,
    const float* __restrict__ Wv, const float* __restrict__ Wp,
    const float* __restrict__ mask, const float* __restrict__ mask_block,
    ushort* __restrict__ Aq, ushort* __restrict__ Ak, ushort* __restrict__ Av,
    ushort* __restrict__ Wb, int* __restrict__ nk, int* __restrict__ inv) {
  const int b = blockIdx.x, t = threadIdx.x;
  if (b < 260) {
    __shared__ float sback[C_DIM];
    if (b == 256) {                         // back token for row 4098
      float cs = 0.f;
      for (int i = (t & 63); i < 128; i += 64) cs += cnt_part[i];
#pragma unroll
      for (int d = 1; d < 64; d <<= 1) cs += __shfl_xor(cs, d);
      const float ic = 1.f / (cs + 1e-10f);
      for (int c = t; c < C_DIM; c += 256) {
        float s = 0.f;
        for (int p = 0; p < 128; ++p) s += pooled_part[p * C_DIM + c];
        sback[c] = s * ic;
      }
      __syncthreads();
    }
    const int r0 = b * 16;
#pragma unroll
    for (int i = 0; i < 6; ++i) {
      const int idx = i * 1024 + t * 4;
      const int row = r0 + idx / C_DIM, col = idx % C_DIM;
      if (row >= NK_TOK) continue;
      const float4 pv = *(const float4*)&pos[(size_t)row * C_DIM + col];
      float4 xv;
      if (row == NK_TOK - 1)
        xv = make_float4(sback[col], sback[col + 1], sback[col + 2], sback[col + 3]);
      else
        xv = *(const float4*)&x[(size_t)row * C_DIM + col];
      if (row < N_TOK) {
        u4 q4 = {f2bf((xv.x + pv.x) * QSCALE), f2bf((xv.y + pv.y) * QSCALE),
                 f2bf((xv.z + pv.z) * QSCALE), f2bf((xv.w + pv.w) * QSCALE)};
        *(u4*)&Aq[(size_t)row * C_DIM + col] = q4;
      }
      u4 k4 = {f2bf(xv.x + pv.x), f2bf(xv.y + pv.y),
               f2bf(xv.z + pv.z), f2bf(xv.w + pv.w)};
      *(u4*)&Ak[(size_t)row * C_DIM + col] = k4;
      u4 v4 = {f2bf(xv.x), f2bf(xv.y), f2bf(xv.z), f2bf(xv.w)};
      *(u4*)&Av[(size_t)row * C_DIM + col] = v4;
    }
  } else if (b < 292) {
    const int wi = b - 260;                  // 0..31; 8 blocks per weight
    const float* src = (wi < 8) ? Wq : (wi < 16) ? Wk : (wi < 24) ? Wv : Wp;
    const int base = (wi >> 3) * 147456 + (wi & 7) * 18432;
#pragma unroll 2
    for (int i = 0; i < 18; ++i) {
      const int g = base + i * 1024 + t * 4;
      const float4 v = *(const float4*)&src[(wi & 7) * 18432 + i * 1024 + t * 4];
      u4 o = {f2bf(v.x), f2bf(v.y), f2bf(v.z), f2bf(v.w)};
      *(u4*)&Wb[g] = o;
    }
  } else {
    // keep-compaction: 256 threads x 17 elements, block prefix scan
    __shared__ int scnt[256];
    const int j0 = t * 17;
    unsigned int bits = 0;
    int c = 0;
#pragma unroll 1
    for (int u = 0; u < 17; ++u) {
      const int j = j0 + u;
      bool keep = false;
      if (j < NK_TOK)
        keep = (j >= 1 && j <= N_TOK - 2) ? (mask[j - 1] >= 0.5f)
                                          : (mask_block[j] >= 0.5f);
      if (keep) { bits |= 1u << u; ++c; }
    }
    scnt[t] = c;
    __syncthreads();
    for (int d = 1; d < 256; d <<= 1) {
      const int v = scnt[t];
      const int add = (t >= d) ? scnt[t - d] : 0;
      __syncthreads();
      scnt[t] = v + add;
      __syncthreads();
    }
    int base = scnt[t] - c;                  // exclusive prefix
    if (t == 255) *nk = scnt[255];
#pragma unroll 1
    for (int u = 0; u < 17; ++u) {
      const int j = j0 + u;
      if (j < NK_TOK) inv[j] = ((bits >> u) & 1) ? base++ : -1;
    }
  }
}

// ---------------------------------------------------------------------------
// bf16 MFMA GEMM core, HEAD-PAIRED: one 64-row A tile shared by TWO 64-col
// B tiles (two heads). The A fragments (8 of 10 LDS frag reads per kt) are
// amortized over 2x the MFMAs vs one-head blocks; barriers per output halve.
// K=384, BK=64, synchronous u8 staging with VGPR prefetch. LDS 27.6 KB.
static __device__ __forceinline__ void gemm_core2(
    const ushort* __restrict__ A, const ushort* __restrict__ B0,
    const ushort* __restrict__ B1,
    ushort (* __restrict__ As)[72], ushort (* __restrict__ Bs0)[72],
    ushort (* __restrict__ Bs1)[72],
    int t, int w, int quad, int l15, f32x4 acc[2][4]) {
  const int g = t & 7;
  const int r = t >> 3;                      // 0..31
  u8 ra[2], rb0[2], rb1[2];
#pragma unroll
  for (int it = 0; it < 2; ++it) {
    ra[it]  = *(const u8*)&A[(it * 32 + r) * C_DIM + g * 8];
    rb0[it] = *(const u8*)&B0[(it * 32 + r) * C_DIM + g * 8];
    rb1[it] = *(const u8*)&B1[(it * 32 + r) * C_DIM + g * 8];
  }
#pragma unroll 1
  for (int kt = 0; kt < 6; ++kt) {
    __syncthreads();                         // previous chunk's readers done
#pragma unroll
    for (int it = 0; it < 2; ++it) {
      *(u8*)&As[it * 32 + r][g * 8]  = ra[it];
      *(u8*)&Bs0[it * 32 + r][g * 8] = rb0[it];
      *(u8*)&Bs1[it * 32 + r][g * 8] = rb1[it];
    }
    __syncthreads();
    if (kt < 5) {                            // prefetch next K-chunk into VGPRs
      const int k0 = (kt + 1) * 64;
#pragma unroll
      for (int it = 0; it < 2; ++it) {
        ra[it]  = *(const u8*)&A[(it * 32 + r) * C_DIM + k0 + g * 8];
        rb0[it] = *(const u8*)&B0[(it * 32 + r) * C_DIM + k0 + g * 8];
        rb1[it] = *(const u8*)&B1[(it * 32 + r) * C_DIM + k0 + g * 8];
      }
    }
    const bh8 b00 = *(const bh8*)&Bs0[w * 16 + l15][quad * 8];
    const bh8 b01 = *(const bh8*)&Bs0[w * 16 + l15][32 + quad * 8];
    const bh8 b10 = *(const bh8*)&Bs1[w * 16 + l15][quad * 8];
    const bh8 b11 = *(const bh8*)&Bs1[w * 16 + l15][32 + quad * 8];
#pragma unroll
    for (int mb = 0; mb < 4; ++mb) {
      const bh8 a0 = *(const bh8*)&As[mb * 16 + l15][quad * 8];
      const bh8 a1 = *(const bh8*)&As[mb * 16 + l15][32 + quad * 8];
      acc[0][mb] = __builtin_amdgcn_mfma_f32_16x16x32_bf16(a0, b00, acc[0][mb], 0, 0, 0);
      acc[0][mb] = __builtin_amdgcn_mfma_f32_16x16x32_bf16(a1, b01, acc[0][mb], 0, 0, 0);
      acc[1][mb] = __builtin_amdgcn_mfma_f32_16x16x32_bf16(a0, b10, acc[1][mb], 0, 0, 0);
      acc[1][mb] = __builtin_amdgcn_mfma_f32_16x16x32_bf16(a1, b11, acc[1][mb], 0, 0, 0);
    }
  }
}

// fused Q/K/V projection, 2 heads per block. y = which*3 + hpair.
// K epilogue scatters compacted rows via inv[] (row-major Kc); V epilogue
// writes transposed Vt directly.
__global__ __launch_bounds__(256) void gemm3_kernel(
    const ushort* __restrict__ Aq, const ushort* __restrict__ Ak,
    const ushort* __restrict__ Av, const ushort* __restrict__ Wb,
    const int* __restrict__ inv, ushort* __restrict__ Qh,
    ushort* __restrict__ Kc, ushort* __restrict__ Vt) {
  __shared__ ushort As[64][72], Bs0[64][72], Bs1[64][72];
  const int t = threadIdx.x, w = t >> 6, lane = t & 63;
  const int quad = lane >> 4, l15 = lane & 15;
  const int m0 = blockIdx.x * 64;
  const int which = blockIdx.y / 3, h0 = (blockIdx.y % 3) * 2;
  const ushort* A = (which == 0 ? Aq : which == 1 ? Ak : Av) + (size_t)m0 * C_DIM;
  const ushort* B0 = Wb + (size_t)which * 147456 + (size_t)h0 * 64 * C_DIM;
  const ushort* B1 = B0 + (size_t)64 * C_DIM;
  f32x4 acc[2][4];
#pragma unroll
  for (int hh = 0; hh < 2; ++hh)
#pragma unroll
    for (int i = 0; i < 4; ++i) acc[hh][i] = (f32x4){0.f, 0.f, 0.f, 0.f};
  gemm_core2(A, B0, B1, As, Bs0, Bs1, t, w, quad, l15, acc);
  const int n = w * 16 + l15;
#pragma unroll
  for (int hh = 0; hh < 2; ++hh) {
    const int h = h0 + hh;
    if (which == 0) {
#pragma unroll
      for (int mb = 0; mb < 4; ++mb)
#pragma unroll
        for (int r = 0; r < 4; ++r) {
          const int m = m0 + mb * 16 + quad * 4 + r;
          if (m < N_TOK) Qh[((size_t)h * N_TOK + m) * 64 + n] = f2bf(acc[hh][mb][r]);
        }
    } else if (which == 1) {
#pragma unroll
      for (int mb = 0; mb < 4; ++mb)
#pragma unroll
        for (int r = 0; r < 4; ++r) {
          const int m = m0 + mb * 16 + quad * 4 + r;
          if (m < NK_TOK) {
            const int slot = inv[m];
            if (slot >= 0) Kc[((size_t)h * NKPAD + slot) * 64 + n] = f2bf(acc[hh][mb][r]);
          }
        }
    } else {
      // V: write transposed layout [h][d=n][slot] directly (fused vtrans)
#pragma unroll
      for (int mb = 0; mb < 4; ++mb)
#pragma unroll
        for (int r = 0; r < 4; ++r) {
          const int m = m0 + mb * 16 + quad * 4 + r;
          if (m < NK_TOK) {
            const int slot = inv[m];
            if (slot >= 0) Vt[((size_t)h * 64 + n) * NKPAD + slot] = f2bf(acc[hh][mb][r]);
          }
        }
    }
  }
}

// output projection, 2 heads per block: fp32 out + bias
__global__ __launch_bounds__(256) void gemm_out_kernel(
    const ushort* __restrict__ Am, const ushort* __restrict__ Wpb,
    const float* __restrict__ bp, float* __restrict__ out) {
  __shared__ ushort As[64][72], Bs0[64][72], Bs1[64][72];
  const int t = threadIdx.x, w = t >> 6, lane = t & 63;
  const int quad = lane >> 4, l15 = lane & 15;
  const int m0 = blockIdx.x * 64;
  const int h0 = blockIdx.y * 2;
  const ushort* B0 = Wpb + (size_t)h0 * 64 * C_DIM;
  f32x4 acc[2][4];
#pragma unroll
  for (int hh = 0; hh < 2; ++hh)
#pragma unroll
    for (int i = 0; i < 4; ++i) acc[hh][i] = (f32x4){0.f, 0.f, 0.f, 0.f};
  gemm_core2(Am + (size_t)m0 * C_DIM, B0, B0 + (size_t)64 * C_DIM,
             As, Bs0, Bs1, t, w, quad, l15, acc);
  const int n = w * 16 + l15;
#pragma unroll
  for (int hh = 0; hh < 2; ++hh) {
    const int h = h0 + hh;
    const float bb = bp[h * 64 + n];
#pragma unroll
    for (int mb = 0; mb < 4; ++mb)
#pragma unroll
      for (int r = 0; r < 4; ++r) {
        const int m = m0 + mb * 16 + quad * 4 + r;
        if (m < N_TOK) out[(size_t)m * C_DIM + h * 64 + n] = acc[hh][mb][r] + bb;
      }
  }
}

// ---------------------------------------------------------------------------
// MFMA flash attention: 128 q per block (2 q-frags/wave); LDS-staged K/V
// (measured best structure) with VGPR prefetch via loop-carried pointers;
// exp2-domain softmax; v_cvt_pk_bf16_f32 P-packing.
// grid (33 q-tiles of 128, 6 heads, NSLICE=6 key slices).
__global__ __launch_bounds__(256) void attn_kernel(
    const ushort* __restrict__ Qh, const ushort* __restrict__ Kc,
    const ushort* __restrict__ Vt, const int* __restrict__ nkp,
    ushort* __restrict__ Opart, float* __restrict__ Lpart) {
  __shared__ ushort Ks[64][72];      // [slot][d]
  __shared__ ushort Vs[64][72];      // [d][slot]
  __shared__ ushort Ps[4][32][72];   // per-wave P^T staging, 2 q-frags
  const int t = threadIdx.x, w = t >> 6, lane = t & 63;
  const int quad = lane >> 4, l15 = lane & 15;
  const int h = blockIdx.y, slice = blockIdx.z;
  const int q0 = blockIdx.x * 128;
  const int nk = *nkp, nchunk = (nk + 63) >> 6;
  const int g = t & 7;

  bh8 qf[2][2];
#pragma unroll
  for (int qa = 0; qa < 2; ++qa) {
    int qr = q0 + w * 32 + qa * 16 + l15;
    if (qr > N_TOK - 1) qr = N_TOK - 1;      // clamp (stores guarded)
    const ushort* qp = Qh + ((size_t)h * N_TOK + qr) * 64 + quad * 8;
    qf[qa][0] = *(const bh8*)qp;
    qf[qa][1] = *(const bh8*)(qp + 32);
  }
  f32x4 oacc[2][4];
#pragma unroll
  for (int qa = 0; qa < 2; ++qa)
#pragma unroll
    for (int i = 0; i < 4; ++i) oacc[qa][i] = (f32x4){0.f, 0.f, 0.f, 0.f};
  float l_r[2] = {0.f, 0.f};

  const ushort* kb = Kc + (size_t)h * NKPAD * 64;
  const ushort* vb = Vt + (size_t)h * 64 * NKPAD;

  // loop-carried staging pointers (strength-reduced addressing)
  const ushort* kstage = kb + ((size_t)slice * 64 + (t >> 3)) * 64 + g * 8;
  const ushort* vstage = vb + (size_t)(t >> 3) * NKPAD + slice * 64 + g * 8;

  u8 rk[2], rv[2];
  if (slice < nchunk) {
    rk[0] = *(const u8*)kstage;
    rk[1] = *(const u8*)(kstage + 32 * 64);
    rv[0] = *(const u8*)vstage;
    rv[1] = *(const u8*)(vstage + (size_t)32 * NKPAD);
  }
#pragma unroll 1
  for (int kc = slice; kc < nchunk; kc += NSLICE) {
    __syncthreads();                          // previous chunk's readers done
    {
      const int r = t >> 3;
      *(u8*)&Ks[r][g * 8] = rk[0];
      *(u8*)&Ks[32 + r][g * 8] = rk[1];
      *(u8*)&Vs[r][g * 8] = rv[0];
      *(u8*)&Vs[32 + r][g * 8] = rv[1];
    }
    __syncthreads();
    if (kc + NSLICE < nchunk) {               // prefetch next chunk into VGPRs
      kstage += NSLICE * 64 * 64;
      vstage += NSLICE * 64;
      rk[0] = *(const u8*)kstage;
      rk[1] = *(const u8*)(kstage + 32 * 64);
      rv[0] = *(const u8*)vstage;
      rv[1] = *(const u8*)(vstage + (size_t)32 * NKPAD);
    }
    float csum[2] = {0.f, 0.f};
#pragma unroll
    for (int f = 0; f < 4; ++f) {
      const bh8 a0 = *(const bh8*)&Ks[f * 16 + l15][quad * 8];
      const bh8 a1 = *(const bh8*)&Ks[f * 16 + l15][32 + quad * 8];
      f32x4 s4[2];
#pragma unroll
      for (int qa = 0; qa < 2; ++qa) {
        s4[qa] = (f32x4){0.f, 0.f, 0.f, 0.f};
        s4[qa] = __builtin_amdgcn_mfma_f32_16x16x32_bf16(a0, qf[qa][0], s4[qa], 0, 0, 0);
        s4[qa] = __builtin_amdgcn_mfma_f32_16x16x32_bf16(a1, qf[qa][1], s4[qa], 0, 0, 0);
      }
      const int keyb = kc * 64 + f * 16 + quad * 4;
#pragma unroll
      for (int qa = 0; qa < 2; ++qa) {
        const float p0 = (keyb + 0 < nk) ? __builtin_amdgcn_exp2f(s4[qa][0]) : 0.f;
        const float p1 = (keyb + 1 < nk) ? __builtin_amdgcn_exp2f(s4[qa][1]) : 0.f;
        const float p2 = (keyb + 2 < nk) ? __builtin_amdgcn_exp2f(s4[qa][2]) : 0.f;
        const float p3 = (keyb + 3 < nk) ? __builtin_amdgcn_exp2f(s4[qa][3]) : 0.f;
        csum[qa] += (p0 + p1) + (p2 + p3);
        unsigned int lo, hi;
        asm("v_cvt_pk_bf16_f32 %0, %1, %2" : "=v"(lo) : "v"(p0), "v"(p1));
        asm("v_cvt_pk_bf16_f32 %0, %1, %2" : "=v"(hi) : "v"(p2), "v"(p3));
        uint2 pk;
        pk.x = lo; pk.y = hi;
        *(uint2*)&Ps[w][qa * 16 + l15][f * 16 + quad * 4] = pk;
      }
    }
#pragma unroll
    for (int qa = 0; qa < 2; ++qa) {
      csum[qa] += __shfl_xor(csum[qa], 16);
      csum[qa] += __shfl_xor(csum[qa], 32);
      l_r[qa] += csum[qa];
    }

    bh8 pa[2][2];
#pragma unroll
    for (int qa = 0; qa < 2; ++qa) {
      pa[qa][0] = *(const bh8*)&Ps[w][qa * 16 + l15][quad * 8];
      pa[qa][1] = *(const bh8*)&Ps[w][qa * 16 + l15][32 + quad * 8];
    }
#pragma unroll
    for (int db = 0; db < 4; ++db) {
      const bh8 b0 = *(const bh8*)&Vs[db * 16 + l15][quad * 8];
      const bh8 b1 = *(const bh8*)&Vs[db * 16 + l15][32 + quad * 8];
#pragma unroll
      for (int qa = 0; qa < 2; ++qa) {
        oacc[qa][db] = __builtin_amdgcn_mfma_f32_16x16x32_bf16(pa[qa][0], b0, oacc[qa][db], 0, 0, 0);
        oacc[qa][db] = __builtin_amdgcn_mfma_f32_16x16x32_bf16(pa[qa][1], b1, oacc[qa][db], 0, 0, 0);
      }
    }
  }

  const int sh = slice * 6 + h;
#pragma unroll
  for (int qa = 0; qa < 2; ++qa) {
    const int qg = q0 + w * 32 + qa * 16;
#pragma unroll
    for (int db = 0; db < 4; ++db)
#pragma unroll
      for (int r = 0; r < 4; ++r) {
        const int q = qg + quad * 4 + r;
        if (q < N_TOK)
          Opart[((size_t)sh * NKPAD + q) * 64 + db * 16 + l15] = f2bf(oacc[qa][db][r]);
      }
    if (quad == 0) {
      const int q = qg + l15;
      if (q < N_TOK) Lpart[sh * NKPAD + q] = l_r[qa];
    }
  }
}

// merge NSLICE key-slice partials -> bf16 Am [4160][384]
__global__ __launch_bounds__(256) void merge_kernel(const ushort* __restrict__ Opart,
                                                    const float* __restrict__ Lpart,
                                                    ushort* __restrict__ Am) {
  const int idx = blockIdx.x * 256 + threadIdx.x;     // u8 chunk index
  if (idx >= N_TOK * 48) return;
  const int q = idx / 48, c = (idx % 48) * 8;
  const int h = c >> 6, d = c & 63;
  float l = 0.f;
#pragma unroll
  for (int s = 0; s < NSLICE; ++s) l += Lpart[(s * 6 + h) * NKPAD + q];
  const float inv = 1.f / l;
  float o[8] = {0.f, 0.f, 0.f, 0.f, 0.f, 0.f, 0.f, 0.f};
#pragma unroll
  for (int s = 0; s < NSLICE; ++s) {
    const u8 v = *(const u8*)&Opart[((size_t)(s * 6 + h) * NKPAD + q) * 64 + d];
#pragma unroll
    for (int j = 0; j < 8; ++j) o[j] += bf2f(v[j]);
  }
  u8 r;
#pragma unroll
  for (int j = 0; j < 8; ++j) r[j] = f2bf(o[j] * inv);
  *(u8*)&Am[(size_t)q * C_DIM + c] = r;
}

// ---------------------------------------------------------------------------
extern "C" void kernel_launch(void* const* d_in, const int* in_sizes, int n_in,
                              void* d_out, int out_size, void* d_ws, size_t ws_size,
                              hipStream_t stream) {
  const float* x          = (const float*)d_in[0];
  const float* pos        = (const float*)d_in[1];
  const float* mask       = (const float*)d_in[2];
  const float* mask_block = (const float*)d_in[3];
  const float* Wq         = (const float*)d_in[4];
  const float* Wk         = (const float*)d_in[5];
  const float* Wv         = (const float*)d_in[6];
  const float* Wp         = (const float*)d_in[7];
  const float* bp         = (const float*)d_in[8];
  float* out = (float*)d_out;
  char* wsb = (char*)d_ws;

  float*  pooled_part = (float*)wsb;                // [128][384]
  float*  cnt_part    = (float*)(wsb + 196608);     // [128]
  int*    nk          = (int*)(wsb + 197120);
  int*    inv         = (int*)(wsb + 197632);       // [4099]
  ushort* Aq          = (ushort*)(wsb + 215296);    // [4160][384]
  ushort* Ak          = (ushort*)(wsb + 3410176);   // [4160][384]
  ushort* Av          = (ushort*)(wsb + 6605056);   // [4160][384]
  ushort* Wb          = (ushort*)(wsb + 9799936);   // [4][384][384]
  ushort* Qh          = (ushort*)(wsb + 10979584);  // [6][4098][64]
  ushort* Kc          = (ushort*)(wsb + 14126848);  // [6][4160][64]
  ushort* Vt          = (ushort*)(wsb + 17321728);  // [6][64][4160]
  ushort* Am          = (ushort*)(wsb + 24011008);  // [4160][384]
  ushort* Op          = (ushort*)(wsb + 27205888);  // [36][4160][64]
  float*  Lp          = (float*)(wsb + 46375168);   // [36][4160]

  pool_kernel<<<dim3(128), dim3(384), 0, stream>>>(x, mask, pooled_part, cnt_part);
  prep_kernel<<<dim3(293), dim3(256), 0, stream>>>(x, pos, pooled_part, cnt_part,
                                                   Wq, Wk, Wv, Wp, mask, mask_block,
                                                   Aq, Ak, Av, Wb, nk, inv);
  gemm3_kernel<<<dim3(65, 9), 256, 0, stream>>>(Aq, Ak, Av, Wb, inv, Qh, Kc, Vt);
  attn_kernel<<<dim3(33, 6, NSLICE), 256, 0, stream>>>(Qh, Kc, Vt, nk, Op, Lp);
  merge_kernel<<<dim3(769), 256, 0, stream>>>(Op, Lp, Am);
  gemm_out_kernel<<<dim3(65, 3), 256, 0, stream>>>(Am, Wb + 3 * 147456, bp, out);
}

// Round 8
// 150.411 us; speedup vs baseline: 1.0660x; 1.0277x over previous
//
#include <hip/hip_runtime.h>
#include <math.h>

#define N_TOK 4098
#define NK_TOK 4099
#define C_DIM 384
#define NKPAD 4160
#define NSLICE 5
// HEADS = 6, HD = 64

typedef short  bh8 __attribute__((ext_vector_type(8)));   // 8 bf16 (4 VGPRs)
typedef float  f32x4 __attribute__((ext_vector_type(4)));
typedef unsigned short ushort;
typedef ushort u4 __attribute__((ext_vector_type(4)));
typedef ushort u8 __attribute__((ext_vector_type(8)));

static __device__ __forceinline__ ushort f2bf(float f) {
  unsigned int u = __float_as_uint(f);
  u = (u + 0x7FFF + ((u >> 16) & 1)) >> 16;   // RNE
  return (ushort)u;
}
static __device__ __forceinline__ float bf2f(ushort s) {
  return __uint_as_float(((unsigned int)s) << 16);
}

// Q pre-scale: D^-0.5 * log2(e); attention exp computed as exp2
#define QSCALE 0.18033688011112042f

// ---------------------------------------------------------------------------
// pool partials (no atomics, no memset needed)
__global__ __launch_bounds__(384) void pool_kernel(
    const float* __restrict__ x, const float* __restrict__ mask,
    float* __restrict__ pooled_part, float* __restrict__ cnt_part) {
  const int b = blockIdx.x, t = threadIdx.x;
  const int r0 = b * 32;
  float acc = 0.f;
  int lc = 0;
  for (int r = r0; r < r0 + 32; ++r)
    if (mask[r] < 0.5f) { acc += x[(size_t)(r + 1) * C_DIM + t]; ++lc; }
  pooled_part[b * C_DIM + t] = acc;
  if (t == 0) cnt_part[b] = (float)lc;
}

// ---------------------------------------------------------------------------
// prep: blocks 0..259 build bf16 A-matrices (16 rows each); block 256 first
// reduces pool partials -> back token (row 4098). blocks 260..291 convert W.
// block 292: single-block keep-compaction prefix scan -> inv[], nk.
__global__ __launch_bounds__(256) void prep_kernel(
    const float* __restrict__ x, const float* __restrict__ pos,
    const float* __restrict__ pooled_part, const float* __restrict__ cnt_part,
    const float* __restrict__ Wq, const float* __restrict__ Wk,
    const float* __restrict__ Wv, const float* __restrict__ Wp,
    const float* __restrict__ mask, const float* __restrict__ mask_block,
    ushort* __restrict__ Aq, ushort* __restrict__ Ak, ushort* __restrict__ Av,
    ushort* __restrict__ Wb, int* __restrict__ nk, int* __restrict__ inv) {
  const int b = blockIdx.x, t = threadIdx.x;
  if (b < 260) {
    __shared__ float sback[C_DIM];
    if (b == 256) {                         // back token for row 4098
      float cs = 0.f;
      for (int i = (t & 63); i < 128; i += 64) cs += cnt_part[i];
#pragma unroll
      for (int d = 1; d < 64; d <<= 1) cs += __shfl_xor(cs, d);
      const float ic = 1.f / (cs + 1e-10f);
      for (int c = t; c < C_DIM; c += 256) {
        float s = 0.f;
        for (int p = 0; p < 128; ++p) s += pooled_part[p * C_DIM + c];
        sback[c] = s * ic;
      }
      __syncthreads();
    }
    const int r0 = b * 16;
#pragma unroll
    for (int i = 0; i < 6; ++i) {
      const int idx = i * 1024 + t * 4;
      const int row = r0 + idx / C_DIM, col = idx % C_DIM;
      if (row >= NK_TOK) continue;
      const float4 pv = *(const float4*)&pos[(size_t)row * C_DIM + col];
      float4 xv;
      if (row == NK_TOK - 1)
        xv = make_float4(sback[col], sback[col + 1], sback[col + 2], sback[col + 3]);
      else
        xv = *(const float4*)&x[(size_t)row * C_DIM + col];
      if (row < N_TOK) {
        u4 q4 = {f2bf((xv.x + pv.x) * QSCALE), f2bf((xv.y + pv.y) * QSCALE),
                 f2bf((xv.z + pv.z) * QSCALE), f2bf((xv.w + pv.w) * QSCALE)};
        *(u4*)&Aq[(size_t)row * C_DIM + col] = q4;
      }
      u4 k4 = {f2bf(xv.x + pv.x), f2bf(xv.y + pv.y),
               f2bf(xv.z + pv.z), f2bf(xv.w + pv.w)};
      *(u4*)&Ak[(size_t)row * C_DIM + col] = k4;
      u4 v4 = {f2bf(xv.x), f2bf(xv.y), f2bf(xv.z), f2bf(xv.w)};
      *(u4*)&Av[(size_t)row * C_DIM + col] = v4;
    }
  } else if (b < 292) {
    const int wi = b - 260;                  // 0..31; 8 blocks per weight
    const float* src = (wi < 8) ? Wq : (wi < 16) ? Wk : (wi < 24) ? Wv : Wp;
    const int base = (wi >> 3) * 147456 + (wi & 7) * 18432;
#pragma unroll 2
    for (int i = 0; i < 18; ++i) {
      const int g = base + i * 1024 + t * 4;
      const float4 v = *(const float4*)&src[(wi & 7) * 18432 + i * 1024 + t * 4];
      u4 o = {f2bf(v.x), f2bf(v.y), f2bf(v.z), f2bf(v.w)};
      *(u4*)&Wb[g] = o;
    }
  } else {
    // keep-compaction: 256 threads x 17 elements, block prefix scan
    __shared__ int scnt[256];
    const int j0 = t * 17;
    unsigned int bits = 0;
    int c = 0;
#pragma unroll 1
    for (int u = 0; u < 17; ++u) {
      const int j = j0 + u;
      bool keep = false;
      if (j < NK_TOK)
        keep = (j >= 1 && j <= N_TOK - 2) ? (mask[j - 1] >= 0.5f)
                                          : (mask_block[j] >= 0.5f);
      if (keep) { bits |= 1u << u; ++c; }
    }
    scnt[t] = c;
    __syncthreads();
    for (int d = 1; d < 256; d <<= 1) {
      const int v = scnt[t];
      const int add = (t >= d) ? scnt[t - d] : 0;
      __syncthreads();
      scnt[t] = v + add;
      __syncthreads();
    }
    int base = scnt[t] - c;                  // exclusive prefix
    if (t == 255) *nk = scnt[255];
#pragma unroll 1
    for (int u = 0; u < 17; ++u) {
      const int j = j0 + u;
      if (j < NK_TOK) inv[j] = ((bits >> u) & 1) ? base++ : -1;
    }
  }
}

// ---------------------------------------------------------------------------
// bf16 MFMA GEMM core: 64x64 out tile, K=384, BK=64, synchronous u8 staging
// with VGPR prefetch of the next K-chunk during compute. Padded LDS [64][72].
static __device__ __forceinline__ void gemm_core(
    const ushort* __restrict__ A, const ushort* __restrict__ B,
    ushort (* __restrict__ As)[72], ushort (* __restrict__ Bs)[72],
    int t, int w, int quad, int l15, f32x4 acc[4]) {
  const int g = t & 7;
  u8 ra[2], rb[2];
#pragma unroll
  for (int it = 0; it < 2; ++it) {
    const int r = it * 32 + (t >> 3);
    ra[it] = *(const u8*)&A[r * C_DIM + g * 8];
    rb[it] = *(const u8*)&B[r * C_DIM + g * 8];
  }
#pragma unroll 1
  for (int kt = 0; kt < 6; ++kt) {
    __syncthreads();                         // previous chunk's readers done
#pragma unroll
    for (int it = 0; it < 2; ++it) {
      const int r = it * 32 + (t >> 3);
      *(u8*)&As[r][g * 8] = ra[it];
      *(u8*)&Bs[r][g * 8] = rb[it];
    }
    __syncthreads();
    if (kt < 5) {
      const int k0 = (kt + 1) * 64;
#pragma unroll
      for (int it = 0; it < 2; ++it) {
        const int r = it * 32 + (t >> 3);
        ra[it] = *(const u8*)&A[r * C_DIM + k0 + g * 8];
        rb[it] = *(const u8*)&B[r * C_DIM + k0 + g * 8];
      }
    }
    const bh8 b0 = *(const bh8*)&Bs[w * 16 + l15][quad * 8];
    const bh8 b1 = *(const bh8*)&Bs[w * 16 + l15][32 + quad * 8];
#pragma unroll
    for (int mb = 0; mb < 4; ++mb) {
      const bh8 a0 = *(const bh8*)&As[mb * 16 + l15][quad * 8];
      const bh8 a1 = *(const bh8*)&As[mb * 16 + l15][32 + quad * 8];
      acc[mb] = __builtin_amdgcn_mfma_f32_16x16x32_bf16(a0, b0, acc[mb], 0, 0, 0);
      acc[mb] = __builtin_amdgcn_mfma_f32_16x16x32_bf16(a1, b1, acc[mb], 0, 0, 0);
    }
  }
}

// fused Q/K/V projection. y = which*6 + h. K epilogue scatters compacted
// rows via inv[] (row-major Kc); V epilogue writes transposed Vt directly.
__global__ __launch_bounds__(256) void gemm3_kernel(
    const ushort* __restrict__ Aq, const ushort* __restrict__ Ak,
    const ushort* __restrict__ Av, const ushort* __restrict__ Wb,
    const int* __restrict__ inv, ushort* __restrict__ Qh,
    ushort* __restrict__ Kc, ushort* __restrict__ Vt) {
  __shared__ ushort As[64][72], Bs[64][72];
  const int t = threadIdx.x, w = t >> 6, lane = t & 63;
  const int quad = lane >> 4, l15 = lane & 15;
  const int m0 = blockIdx.x * 64;
  const int which = blockIdx.y / 6, h = blockIdx.y % 6;
  const ushort* A = (which == 0 ? Aq : which == 1 ? Ak : Av) + (size_t)m0 * C_DIM;
  const ushort* B = Wb + (size_t)which * 147456 + (size_t)h * 64 * C_DIM;
  f32x4 acc[4];
#pragma unroll
  for (int i = 0; i < 4; ++i) acc[i] = (f32x4){0.f, 0.f, 0.f, 0.f};
  gemm_core(A, B, As, Bs, t, w, quad, l15, acc);
  const int n = w * 16 + l15;
  if (which == 0) {
#pragma unroll
    for (int mb = 0; mb < 4; ++mb)
#pragma unroll
      for (int r = 0; r < 4; ++r) {
        const int m = m0 + mb * 16 + quad * 4 + r;
        if (m < N_TOK) Qh[((size_t)h * N_TOK + m) * 64 + n] = f2bf(acc[mb][r]);
      }
  } else if (which == 1) {
#pragma unroll
    for (int mb = 0; mb < 4; ++mb)
#pragma unroll
      for (int r = 0; r < 4; ++r) {
        const int m = m0 + mb * 16 + quad * 4 + r;
        if (m < NK_TOK) {
          const int slot = inv[m];
          if (slot >= 0) Kc[((size_t)h * NKPAD + slot) * 64 + n] = f2bf(acc[mb][r]);
        }
      }
  } else {
    // V: write transposed layout [h][d=n][slot] directly (fused vtrans)
#pragma unroll
    for (int mb = 0; mb < 4; ++mb)
#pragma unroll
      for (int r = 0; r < 4; ++r) {
        const int m = m0 + mb * 16 + quad * 4 + r;
        if (m < NK_TOK) {
          const int slot = inv[m];
          if (slot >= 0) Vt[((size_t)h * 64 + n) * NKPAD + slot] = f2bf(acc[mb][r]);
        }
      }
  }
}

// output projection: fp32 out + bias
__global__ __launch_bounds__(256) void gemm_out_kernel(
    const ushort* __restrict__ Am, const ushort* __restrict__ Wpb,
    const float* __restrict__ bp, float* __restrict__ out) {
  __shared__ ushort As[64][72], Bs[64][72];
  const int t = threadIdx.x, w = t >> 6, lane = t & 63;
  const int quad = lane >> 4, l15 = lane & 15;
  const int m0 = blockIdx.x * 64;
  const int h = blockIdx.y;
  f32x4 acc[4];
#pragma unroll
  for (int i = 0; i < 4; ++i) acc[i] = (f32x4){0.f, 0.f, 0.f, 0.f};
  gemm_core(Am + (size_t)m0 * C_DIM, Wpb + (size_t)h * 64 * C_DIM,
            As, Bs, t, w, quad, l15, acc);
  const int n = w * 16 + l15;
  const float bb = bp[h * 64 + n];
#pragma unroll
  for (int mb = 0; mb < 4; ++mb)
#pragma unroll
    for (int r = 0; r < 4; ++r) {
      const int m = m0 + mb * 16 + quad * 4 + r;
      if (m < N_TOK) out[(size_t)m * C_DIM + h * 64 + n] = acc[mb][r] + bb;
    }
}

// ---------------------------------------------------------------------------
// MFMA flash attention: 8 waves x 32 q = 256 q per block. One K/V stage +
// 2 barriers per chunk now feeds 8 waves' MFMAs (2x amortization vs the
// 4-wave version) while waves/CU stays 16 (LDS 55.3 KB -> 2 blocks/CU x 8
// waves) -- the R5/R6 lesson: hold waves/CU, amortize fixed costs.
// exp2-domain softmax; v_cvt_pk_bf16_f32 P-packing.
// grid (17 q-tiles of 256, 6 heads, NSLICE=5) = 510 blocks ~ 2/CU resident.
__global__ __launch_bounds__(512) void attn_kernel(
    const ushort* __restrict__ Qh, const ushort* __restrict__ Kc,
    const ushort* __restrict__ Vt, const int* __restrict__ nkp,
    ushort* __restrict__ Opart, float* __restrict__ Lpart) {
  __shared__ ushort Ks[64][72];      // [slot][d]
  __shared__ ushort Vs[64][72];      // [d][slot]
  __shared__ ushort Ps[8][32][72];   // per-wave P^T staging, 2 q-frags
  const int t = threadIdx.x, w = t >> 6, lane = t & 63;
  const int quad = lane >> 4, l15 = lane & 15;
  const int h = blockIdx.y, slice = blockIdx.z;
  const int q0 = blockIdx.x * 256;
  const int nk = *nkp, nchunk = (nk + 63) >> 6;
  const int g = t & 7;
  const int sr = t >> 3;             // 0..63 staging row (512 threads)

  bh8 qf[2][2];
#pragma unroll
  for (int qa = 0; qa < 2; ++qa) {
    int qr = q0 + w * 32 + qa * 16 + l15;
    if (qr > N_TOK - 1) qr = N_TOK - 1;      // clamp (stores guarded)
    const ushort* qp = Qh + ((size_t)h * N_TOK + qr) * 64 + quad * 8;
    qf[qa][0] = *(const bh8*)qp;
    qf[qa][1] = *(const bh8*)(qp + 32);
  }
  f32x4 oacc[2][4];
#pragma unroll
  for (int qa = 0; qa < 2; ++qa)
#pragma unroll
    for (int i = 0; i < 4; ++i) oacc[qa][i] = (f32x4){0.f, 0.f, 0.f, 0.f};
  float l_r[2] = {0.f, 0.f};

  const ushort* kb = Kc + (size_t)h * NKPAD * 64;
  const ushort* vb = Vt + (size_t)h * 64 * NKPAD;

  // loop-carried staging pointers (strength-reduced addressing)
  const ushort* kstage = kb + ((size_t)slice * 64 + sr) * 64 + g * 8;
  const ushort* vstage = vb + (size_t)sr * NKPAD + slice * 64 + g * 8;

  u8 rk, rv;
  if (slice < nchunk) {
    rk = *(const u8*)kstage;
    rv = *(const u8*)vstage;
  }
#pragma unroll 1
  for (int kc = slice; kc < nchunk; kc += NSLICE) {
    __syncthreads();                          // previous chunk's readers done
    *(u8*)&Ks[sr][g * 8] = rk;
    *(u8*)&Vs[sr][g * 8] = rv;
    __syncthreads();
    if (kc + NSLICE < nchunk) {               // prefetch next chunk into VGPRs
      kstage += NSLICE * 64 * 64;
      vstage += NSLICE * 64;
      rk = *(const u8*)kstage;
      rv = *(const u8*)vstage;
    }
    float csum[2] = {0.f, 0.f};
#pragma unroll
    for (int f = 0; f < 4; ++f) {
      const bh8 a0 = *(const bh8*)&Ks[f * 16 + l15][quad * 8];
      const bh8 a1 = *(const bh8*)&Ks[f * 16 + l15][32 + quad * 8];
      f32x4 s4[2];
#pragma unroll
      for (int qa = 0; qa < 2; ++qa) {
        s4[qa] = (f32x4){0.f, 0.f, 0.f, 0.f};
        s4[qa] = __builtin_amdgcn_mfma_f32_16x16x32_bf16(a0, qf[qa][0], s4[qa], 0, 0, 0);
        s4[qa] = __builtin_amdgcn_mfma_f32_16x16x32_bf16(a1, qf[qa][1], s4[qa], 0, 0, 0);
      }
      const int keyb = kc * 64 + f * 16 + quad * 4;
#pragma unroll
      for (int qa = 0; qa < 2; ++qa) {
        const float p0 = (keyb + 0 < nk) ? __builtin_amdgcn_exp2f(s4[qa][0]) : 0.f;
        const float p1 = (keyb + 1 < nk) ? __builtin_amdgcn_exp2f(s4[qa][1]) : 0.f;
        const float p2 = (keyb + 2 < nk) ? __builtin_amdgcn_exp2f(s4[qa][2]) : 0.f;
        const float p3 = (keyb + 3 < nk) ? __builtin_amdgcn_exp2f(s4[qa][3]) : 0.f;
        csum[qa] += (p0 + p1) + (p2 + p3);
        unsigned int lo, hi;
        asm("v_cvt_pk_bf16_f32 %0, %1, %2" : "=v"(lo) : "v"(p0), "v"(p1));
        asm("v_cvt_pk_bf16_f32 %0, %1, %2" : "=v"(hi) : "v"(p2), "v"(p3));
        uint2 pk;
        pk.x = lo; pk.y = hi;
        *(uint2*)&Ps[w][qa * 16 + l15][f * 16 + quad * 4] = pk;
      }
    }
#pragma unroll
    for (int qa = 0; qa < 2; ++qa) {
      csum[qa] += __shfl_xor(csum[qa], 16);
      csum[qa] += __shfl_xor(csum[qa], 32);
      l_r[qa] += csum[qa];
    }

    bh8 pa[2][2];
#pragma unroll
    for (int qa = 0; qa < 2; ++qa) {
      pa[qa][0] = *(const bh8*)&Ps[w][qa * 16 + l15][quad * 8];
      pa[qa][1] = *(const bh8*)&Ps[w][qa * 16 + l15][32 + quad * 8];
    }
#pragma unroll
    for (int db = 0; db < 4; ++db) {
      const bh8 b0 = *(const bh8*)&Vs[db * 16 + l15][quad * 8];
      const bh8 b1 = *(const bh8*)&Vs[db * 16 + l15][32 + quad * 8];
#pragma unroll
      for (int qa = 0; qa < 2; ++qa) {
        oacc[qa][db] = __builtin_amdgcn_mfma_f32_16x16x32_bf16(pa[qa][0], b0, oacc[qa][db], 0, 0, 0);
        oacc[qa][db] = __builtin_amdgcn_mfma_f32_16x16x32_bf16(pa[qa][1], b1, oacc[qa][db], 0, 0, 0);
      }
    }
  }

  const int sh = slice * 6 + h;
#pragma unroll
  for (int qa = 0; qa < 2; ++qa) {
    const int qg = q0 + w * 32 + qa * 16;
#pragma unroll
    for (int db = 0; db < 4; ++db)
#pragma unroll
      for (int r = 0; r < 4; ++r) {
        const int q = qg + quad * 4 + r;
        if (q < N_TOK)
          Opart[((size_t)sh * NKPAD + q) * 64 + db * 16 + l15] = f2bf(oacc[qa][db][r]);
      }
    if (quad == 0) {
      const int q = qg + l15;
      if (q < N_TOK) Lpart[sh * NKPAD + q] = l_r[qa];
    }
  }
}

// merge NSLICE key-slice partials -> bf16 Am [4160][384]
__global__ __launch_bounds__(256) void merge_kernel(const ushort* __restrict__ Opart,
                                                    const float* __restrict__ Lpart,
                                                    ushort* __restrict__ Am) {
  const int idx = blockIdx.x * 256 + threadIdx.x;     // u8 chunk index
  if (idx >= N_TOK * 48) return;
  const int q = idx / 48, c = (idx % 48) * 8;
  const int h = c >> 6, d = c & 63;
  float l = 0.f;
#pragma unroll
  for (int s = 0; s < NSLICE; ++s) l += Lpart[(s * 6 + h) * NKPAD + q];
  const float inv = 1.f / l;
  float o[8] = {0.f, 0.f, 0.f, 0.f, 0.f, 0.f, 0.f, 0.f};
#pragma unroll
  for (int s = 0; s < NSLICE; ++s) {
    const u8 v = *(const u8*)&Opart[((size_t)(s * 6 + h) * NKPAD + q) * 64 + d];
#pragma unroll
    for (int j = 0; j < 8; ++j) o[j] += bf2f(v[j]);
  }
  u8 r;
#pragma unroll
  for (int j = 0; j < 8; ++j) r[j] = f2bf(o[j] * inv);
  *(u8*)&Am[(size_t)q * C_DIM + c] = r;
}

// ---------------------------------------------------------------------------
extern "C" void kernel_launch(void* const* d_in, const int* in_sizes, int n_in,
                              void* d_out, int out_size, void* d_ws, size_t ws_size,
                              hipStream_t stream) {
  const float* x          = (const float*)d_in[0];
  const float* pos        = (const float*)d_in[1];
  const float* mask       = (const float*)d_in[2];
  const float* mask_block = (const float*)d_in[3];
  const float* Wq         = (const float*)d_in[4];
  const float* Wk         = (const float*)d_in[5];
  const float* Wv         = (const float*)d_in[6];
  const float* Wp         = (const float*)d_in[7];
  const float* bp         = (const float*)d_in[8];
  float* out = (float*)d_out;
  char* wsb = (char*)d_ws;

  float*  pooled_part = (float*)wsb;                // [128][384]
  float*  cnt_part    = (float*)(wsb + 196608);     // [128]
  int*    nk          = (int*)(wsb + 197120);
  int*    inv         = (int*)(wsb + 197632);       // [4099]
  ushort* Aq          = (ushort*)(wsb + 215296);    // [4160][384]
  ushort* Ak          = (ushort*)(wsb + 3410176);   // [4160][384]
  ushort* Av          = (ushort*)(wsb + 6605056);   // [4160][384]
  ushort* Wb          = (ushort*)(wsb + 9799936);   // [4][384][384]
  ushort* Qh          = (ushort*)(wsb + 10979584);  // [6][4098][64]
  ushort* Kc          = (ushort*)(wsb + 14126848);  // [6][4160][64]
  ushort* Vt          = (ushort*)(wsb + 17321728);  // [6][64][4160]
  ushort* Am          = (ushort*)(wsb + 24011008);  // [4160][384]
  ushort* Op          = (ushort*)(wsb + 27205888);  // [30][4160][64]
  float*  Lp          = (float*)(wsb + 46375168);   // [30][4160]

  pool_kernel<<<dim3(128), dim3(384), 0, stream>>>(x, mask, pooled_part, cnt_part);
  prep_kernel<<<dim3(293), dim3(256), 0, stream>>>(x, pos, pooled_part, cnt_part,
                                                   Wq, Wk, Wv, Wp, mask, mask_block,
                                                   Aq, Ak, Av, Wb, nk, inv);
  gemm3_kernel<<<dim3(65, 18), 256, 0, stream>>>(Aq, Ak, Av, Wb, inv, Qh, Kc, Vt);
  attn_kernel<<<dim3(17, 6, NSLICE), 512, 0, stream>>>(Qh, Kc, Vt, nk, Op, Lp);
  merge_kernel<<<dim3(769), 256, 0, stream>>>(Op, Lp, Am);
  gemm_out_kernel<<<dim3(65, 6), 256, 0, stream>>>(Am, Wb + 3 * 147456, bp, out);
}

// Round 9
// 148.065 us; speedup vs baseline: 1.0829x; 1.0158x over previous
//
#include <hip/hip_runtime.h>
#include <math.h>

#define N_TOK 4098
#define NK_TOK 4099
#define C_DIM 384
#define NKPAD 4160
#define NSLICE 5
// HEADS = 6, HD = 64

typedef short  bh8 __attribute__((ext_vector_type(8)));   // 8 bf16 (4 VGPRs)
typedef float  f32x4 __attribute__((ext_vector_type(4)));
typedef unsigned short ushort;
typedef ushort u4 __attribute__((ext_vector_type(4)));
typedef ushort u8 __attribute__((ext_vector_type(8)));

static __device__ __forceinline__ ushort f2bf(float f) {
  unsigned int u = __float_as_uint(f);
  u = (u + 0x7FFF + ((u >> 16) & 1)) >> 16;   // RNE
  return (ushort)u;
}
static __device__ __forceinline__ float bf2f(ushort s) {
  return __uint_as_float(((unsigned int)s) << 16);
}

// Q scale: D^-0.5 * log2(e), folded into Wq at prep; attention exp = exp2
#define QSCALE 0.18033688011112042f

// ---------------------------------------------------------------------------
// prep: blocks 0..259 build bf16 Ak/Av rows (16 rows each; row 4098 deferred
// to back_kernel); blocks 260..291 convert W (Wq prescaled by QSCALE);
// block 292: keep-compaction prefix scan -> inv[], nk; blocks 293..356:
// pool partials (64 rows each) — fused here so they overlap the A/W blocks.
__global__ __launch_bounds__(256) void prep_kernel(
    const float* __restrict__ x, const float* __restrict__ pos,
    const float* __restrict__ Wq, const float* __restrict__ Wk,
    const float* __restrict__ Wv, const float* __restrict__ Wp,
    const float* __restrict__ mask, const float* __restrict__ mask_block,
    ushort* __restrict__ Ak, ushort* __restrict__ Av,
    ushort* __restrict__ Wb, int* __restrict__ nk, int* __restrict__ inv,
    float* __restrict__ pooled_part, float* __restrict__ cnt_part) {
  const int b = blockIdx.x, t = threadIdx.x;
  if (b < 260) {
    const int r0 = b * 16;
#pragma unroll
    for (int i = 0; i < 6; ++i) {
      const int idx = i * 1024 + t * 4;
      const int row = r0 + idx / C_DIM, col = idx % C_DIM;
      if (row >= NK_TOK - 1) continue;       // row 4098 via back_kernel
      const float4 pv = *(const float4*)&pos[(size_t)row * C_DIM + col];
      const float4 xv = *(const float4*)&x[(size_t)row * C_DIM + col];
      u4 k4 = {f2bf(xv.x + pv.x), f2bf(xv.y + pv.y),
               f2bf(xv.z + pv.z), f2bf(xv.w + pv.w)};
      *(u4*)&Ak[(size_t)row * C_DIM + col] = k4;
      u4 v4 = {f2bf(xv.x), f2bf(xv.y), f2bf(xv.z), f2bf(xv.w)};
      *(u4*)&Av[(size_t)row * C_DIM + col] = v4;
    }
  } else if (b < 292) {
    const int wi = b - 260;                  // 0..31; 8 blocks per weight
    const float* src = (wi < 8) ? Wq : (wi < 16) ? Wk : (wi < 24) ? Wv : Wp;
    const float sc = (wi < 8) ? QSCALE : 1.f;  // fold Q prescale into Wq
    const int base = (wi >> 3) * 147456 + (wi & 7) * 18432;
#pragma unroll 2
    for (int i = 0; i < 18; ++i) {
      const int g = base + i * 1024 + t * 4;
      const float4 v = *(const float4*)&src[(wi & 7) * 18432 + i * 1024 + t * 4];
      u4 o = {f2bf(v.x * sc), f2bf(v.y * sc), f2bf(v.z * sc), f2bf(v.w * sc)};
      *(u4*)&Wb[g] = o;
    }
  } else if (b == 292) {
    // keep-compaction: 256 threads x 17 elements, block prefix scan
    __shared__ int scnt[256];
    const int j0 = t * 17;
    unsigned int bits = 0;
    int c = 0;
#pragma unroll 1
    for (int u = 0; u < 17; ++u) {
      const int j = j0 + u;
      bool keep = false;
      if (j < NK_TOK)
        keep = (j >= 1 && j <= N_TOK - 2) ? (mask[j - 1] >= 0.5f)
                                          : (mask_block[j] >= 0.5f);
      if (keep) { bits |= 1u << u; ++c; }
    }
    scnt[t] = c;
    __syncthreads();
    for (int d = 1; d < 256; d <<= 1) {
      const int v = scnt[t];
      const int add = (t >= d) ? scnt[t - d] : 0;
      __syncthreads();
      scnt[t] = v + add;
      __syncthreads();
    }
    int base = scnt[t] - c;                  // exclusive prefix
    if (t == 255) *nk = scnt[255];
#pragma unroll 1
    for (int u = 0; u < 17; ++u) {
      const int j = j0 + u;
      if (j < NK_TOK) inv[j] = ((bits >> u) & 1) ? base++ : -1;
    }
  } else {
    // pool partials: 64 blocks x 64 mask-rows; threads 0..127 cover 2 chans
    const int pb = b - 293;
    const int r0 = pb * 64;
    float acc0 = 0.f, acc1 = 0.f;
    int lc = 0;
    for (int r = r0; r < r0 + 64; ++r) {
      if (mask[r] < 0.5f) {
        acc0 += x[(size_t)(r + 1) * C_DIM + t];
        if (t < 128) acc1 += x[(size_t)(r + 1) * C_DIM + 256 + t];
        ++lc;
      }
    }
    pooled_part[pb * C_DIM + t] = acc0;
    if (t < 128) pooled_part[pb * C_DIM + 256 + t] = acc1;
    if (t == 0) cnt_part[pb] = (float)lc;
  }
}

// back token: reduce 64 pool partials -> row 4098 of Ak (+pos) and Av
__global__ __launch_bounds__(384) void back_kernel(
    const float* __restrict__ pooled_part, const float* __restrict__ cnt_part,
    const float* __restrict__ pos, ushort* __restrict__ Ak,
    ushort* __restrict__ Av) {
  const int t = threadIdx.x;                 // 0..383 = channel
  float cs = 0.f;
#pragma unroll
  for (int p = 0; p < 64; ++p) cs += cnt_part[p];
  const float ic = 1.f / (cs + 1e-10f);
  float s = 0.f;
  for (int p = 0; p < 64; ++p) s += pooled_part[p * C_DIM + t];
  const float back = s * ic;
  const size_t off = (size_t)(NK_TOK - 1) * C_DIM + t;
  Av[off] = f2bf(back);
  Ak[off] = f2bf(back + pos[off]);
}

// ---------------------------------------------------------------------------
// bf16 MFMA GEMM core: 64x64 out tile, K=384, BK=64, synchronous u8 staging
// with VGPR prefetch of the next K-chunk during compute. Padded LDS [64][72].
static __device__ __forceinline__ void gemm_core(
    const ushort* __restrict__ A, const ushort* __restrict__ B,
    ushort (* __restrict__ As)[72], ushort (* __restrict__ Bs)[72],
    int t, int w, int quad, int l15, f32x4 acc[4]) {
  const int g = t & 7;
  u8 ra[2], rb[2];
#pragma unroll
  for (int it = 0; it < 2; ++it) {
    const int r = it * 32 + (t >> 3);
    ra[it] = *(const u8*)&A[r * C_DIM + g * 8];
    rb[it] = *(const u8*)&B[r * C_DIM + g * 8];
  }
#pragma unroll 1
  for (int kt = 0; kt < 6; ++kt) {
    __syncthreads();                         // previous chunk's readers done
#pragma unroll
    for (int it = 0; it < 2; ++it) {
      const int r = it * 32 + (t >> 3);
      *(u8*)&As[r][g * 8] = ra[it];
      *(u8*)&Bs[r][g * 8] = rb[it];
    }
    __syncthreads();
    if (kt < 5) {
      const int k0 = (kt + 1) * 64;
#pragma unroll
      for (int it = 0; it < 2; ++it) {
        const int r = it * 32 + (t >> 3);
        ra[it] = *(const u8*)&A[r * C_DIM + k0 + g * 8];
        rb[it] = *(const u8*)&B[r * C_DIM + k0 + g * 8];
      }
    }
    const bh8 b0 = *(const bh8*)&Bs[w * 16 + l15][quad * 8];
    const bh8 b1 = *(const bh8*)&Bs[w * 16 + l15][32 + quad * 8];
#pragma unroll
    for (int mb = 0; mb < 4; ++mb) {
      const bh8 a0 = *(const bh8*)&As[mb * 16 + l15][quad * 8];
      const bh8 a1 = *(const bh8*)&As[mb * 16 + l15][32 + quad * 8];
      acc[mb] = __builtin_amdgcn_mfma_f32_16x16x32_bf16(a0, b0, acc[mb], 0, 0, 0);
      acc[mb] = __builtin_amdgcn_mfma_f32_16x16x32_bf16(a1, b1, acc[mb], 0, 0, 0);
    }
  }
}

// fused Q/K/V projection. y = which*6 + h. Q uses Ak with QSCALE-folded Wq.
// K epilogue scatters compacted rows via inv[]; V writes transposed Vt.
__global__ __launch_bounds__(256) void gemm3_kernel(
    const ushort* __restrict__ Ak, const ushort* __restrict__ Av,
    const ushort* __restrict__ Wb, const int* __restrict__ inv,
    ushort* __restrict__ Qh, ushort* __restrict__ Kc, ushort* __restrict__ Vt) {
  __shared__ ushort As[64][72], Bs[64][72];
  const int t = threadIdx.x, w = t >> 6, lane = t & 63;
  const int quad = lane >> 4, l15 = lane & 15;
  const int m0 = blockIdx.x * 64;
  const int which = blockIdx.y / 6, h = blockIdx.y % 6;
  const ushort* A = (which == 2 ? Av : Ak) + (size_t)m0 * C_DIM;
  const ushort* B = Wb + (size_t)which * 147456 + (size_t)h * 64 * C_DIM;
  f32x4 acc[4];
#pragma unroll
  for (int i = 0; i < 4; ++i) acc[i] = (f32x4){0.f, 0.f, 0.f, 0.f};
  gemm_core(A, B, As, Bs, t, w, quad, l15, acc);
  const int n = w * 16 + l15;
  if (which == 0) {
#pragma unroll
    for (int mb = 0; mb < 4; ++mb)
#pragma unroll
      for (int r = 0; r < 4; ++r) {
        const int m = m0 + mb * 16 + quad * 4 + r;
        if (m < N_TOK) Qh[((size_t)h * N_TOK + m) * 64 + n] = f2bf(acc[mb][r]);
      }
  } else if (which == 1) {
#pragma unroll
    for (int mb = 0; mb < 4; ++mb)
#pragma unroll
      for (int r = 0; r < 4; ++r) {
        const int m = m0 + mb * 16 + quad * 4 + r;
        if (m < NK_TOK) {
          const int slot = inv[m];
          if (slot >= 0) Kc[((size_t)h * NKPAD + slot) * 64 + n] = f2bf(acc[mb][r]);
        }
      }
  } else {
    // V: write transposed layout [h][d=n][slot] directly (fused vtrans)
#pragma unroll
    for (int mb = 0; mb < 4; ++mb)
#pragma unroll
      for (int r = 0; r < 4; ++r) {
        const int m = m0 + mb * 16 + quad * 4 + r;
        if (m < NK_TOK) {
          const int slot = inv[m];
          if (slot >= 0) Vt[((size_t)h * 64 + n) * NKPAD + slot] = f2bf(acc[mb][r]);
        }
      }
  }
}

// output projection: fp32 out + bias
__global__ __launch_bounds__(256) void gemm_out_kernel(
    const ushort* __restrict__ Am, const ushort* __restrict__ Wpb,
    const float* __restrict__ bp, float* __restrict__ out) {
  __shared__ ushort As[64][72], Bs[64][72];
  const int t = threadIdx.x, w = t >> 6, lane = t & 63;
  const int quad = lane >> 4, l15 = lane & 15;
  const int m0 = blockIdx.x * 64;
  const int h = blockIdx.y;
  f32x4 acc[4];
#pragma unroll
  for (int i = 0; i < 4; ++i) acc[i] = (f32x4){0.f, 0.f, 0.f, 0.f};
  gemm_core(Am + (size_t)m0 * C_DIM, Wpb + (size_t)h * 64 * C_DIM,
            As, Bs, t, w, quad, l15, acc);
  const int n = w * 16 + l15;
  const float bb = bp[h * 64 + n];
#pragma unroll
  for (int mb = 0; mb < 4; ++mb)
#pragma unroll
    for (int r = 0; r < 4; ++r) {
      const int m = m0 + mb * 16 + quad * 4 + r;
      if (m < N_TOK) out[(size_t)m * C_DIM + h * 64 + n] = acc[mb][r] + bb;
    }
}

// ---------------------------------------------------------------------------
// MFMA flash attention: 8 waves x 32 q = 256 q per block (R8 measured-best).
// One K/V stage + 2 barriers per chunk feeds 8 waves; waves/CU stays 16
// (LDS 55.3 KB -> 2 blocks/CU x 8 waves). exp2-domain softmax;
// v_cvt_pk_bf16_f32 P-packing. grid (17, 6, NSLICE=5) = 510 blocks.
__global__ __launch_bounds__(512) void attn_kernel(
    const ushort* __restrict__ Qh, const ushort* __restrict__ Kc,
    const ushort* __restrict__ Vt, const int* __restrict__ nkp,
    ushort* __restrict__ Opart, float* __restrict__ Lpart) {
  __shared__ ushort Ks[64][72];      // [slot][d]
  __shared__ ushort Vs[64][72];      // [d][slot]
  __shared__ ushort Ps[8][32][72];   // per-wave P^T staging, 2 q-frags
  const int t = threadIdx.x, w = t >> 6, lane = t & 63;
  const int quad = lane >> 4, l15 = lane & 15;
  const int h = blockIdx.y, slice = blockIdx.z;
  const int q0 = blockIdx.x * 256;
  const int nk = *nkp, nchunk = (nk + 63) >> 6;
  const int g = t & 7;
  const int sr = t >> 3;             // 0..63 staging row (512 threads)

  bh8 qf[2][2];
#pragma unroll
  for (int qa = 0; qa < 2; ++qa) {
    int qr = q0 + w * 32 + qa * 16 + l15;
    if (qr > N_TOK - 1) qr = N_TOK - 1;      // clamp (stores guarded)
    const ushort* qp = Qh + ((size_t)h * N_TOK + qr) * 64 + quad * 8;
    qf[qa][0] = *(const bh8*)qp;
    qf[qa][1] = *(const bh8*)(qp + 32);
  }
  f32x4 oacc[2][4];
#pragma unroll
  for (int qa = 0; qa < 2; ++qa)
#pragma unroll
    for (int i = 0; i < 4; ++i) oacc[qa][i] = (f32x4){0.f, 0.f, 0.f, 0.f};
  float l_r[2] = {0.f, 0.f};

  const ushort* kb = Kc + (size_t)h * NKPAD * 64;
  const ushort* vb = Vt + (size_t)h * 64 * NKPAD;

  // loop-carried staging pointers (strength-reduced addressing)
  const ushort* kstage = kb + ((size_t)slice * 64 + sr) * 64 + g * 8;
  const ushort* vstage = vb + (size_t)sr * NKPAD + slice * 64 + g * 8;

  u8 rk, rv;
  if (slice < nchunk) {
    rk = *(const u8*)kstage;
    rv = *(const u8*)vstage;
  }
#pragma unroll 1
  for (int kc = slice; kc < nchunk; kc += NSLICE) {
    __syncthreads();                          // previous chunk's readers done
    *(u8*)&Ks[sr][g * 8] = rk;
    *(u8*)&Vs[sr][g * 8] = rv;
    __syncthreads();
    if (kc + NSLICE < nchunk) {               // prefetch next chunk into VGPRs
      kstage += NSLICE * 64 * 64;
      vstage += NSLICE * 64;
      rk = *(const u8*)kstage;
      rv = *(const u8*)vstage;
    }
    float csum[2] = {0.f, 0.f};
#pragma unroll
    for (int f = 0; f < 4; ++f) {
      const bh8 a0 = *(const bh8*)&Ks[f * 16 + l15][quad * 8];
      const bh8 a1 = *(const bh8*)&Ks[f * 16 + l15][32 + quad * 8];
      f32x4 s4[2];
#pragma unroll
      for (int qa = 0; qa < 2; ++qa) {
        s4[qa] = (f32x4){0.f, 0.f, 0.f, 0.f};
        s4[qa] = __builtin_amdgcn_mfma_f32_16x16x32_bf16(a0, qf[qa][0], s4[qa], 0, 0, 0);
        s4[qa] = __builtin_amdgcn_mfma_f32_16x16x32_bf16(a1, qf[qa][1], s4[qa], 0, 0, 0);
      }
      const int keyb = kc * 64 + f * 16 + quad * 4;
#pragma unroll
      for (int qa = 0; qa < 2; ++qa) {
        const float p0 = (keyb + 0 < nk) ? __builtin_amdgcn_exp2f(s4[qa][0]) : 0.f;
        const float p1 = (keyb + 1 < nk) ? __builtin_amdgcn_exp2f(s4[qa][1]) : 0.f;
        const float p2 = (keyb + 2 < nk) ? __builtin_amdgcn_exp2f(s4[qa][2]) : 0.f;
        const float p3 = (keyb + 3 < nk) ? __builtin_amdgcn_exp2f(s4[qa][3]) : 0.f;
        csum[qa] += (p0 + p1) + (p2 + p3);
        unsigned int lo, hi;
        asm("v_cvt_pk_bf16_f32 %0, %1, %2" : "=v"(lo) : "v"(p0), "v"(p1));
        asm("v_cvt_pk_bf16_f32 %0, %1, %2" : "=v"(hi) : "v"(p2), "v"(p3));
        uint2 pk;
        pk.x = lo; pk.y = hi;
        *(uint2*)&Ps[w][qa * 16 + l15][f * 16 + quad * 4] = pk;
      }
    }
#pragma unroll
    for (int qa = 0; qa < 2; ++qa) {
      csum[qa] += __shfl_xor(csum[qa], 16);
      csum[qa] += __shfl_xor(csum[qa], 32);
      l_r[qa] += csum[qa];
    }

    bh8 pa[2][2];
#pragma unroll
    for (int qa = 0; qa < 2; ++qa) {
      pa[qa][0] = *(const bh8*)&Ps[w][qa * 16 + l15][quad * 8];
      pa[qa][1] = *(const bh8*)&Ps[w][qa * 16 + l15][32 + quad * 8];
    }
#pragma unroll
    for (int db = 0; db < 4; ++db) {
      const bh8 b0 = *(const bh8*)&Vs[db * 16 + l15][quad * 8];
      const bh8 b1 = *(const bh8*)&Vs[db * 16 + l15][32 + quad * 8];
#pragma unroll
      for (int qa = 0; qa < 2; ++qa) {
        oacc[qa][db] = __builtin_amdgcn_mfma_f32_16x16x32_bf16(pa[qa][0], b0, oacc[qa][db], 0, 0, 0);
        oacc[qa][db] = __builtin_amdgcn_mfma_f32_16x16x32_bf16(pa[qa][1], b1, oacc[qa][db], 0, 0, 0);
      }
    }
  }

  const int sh = slice * 6 + h;
#pragma unroll
  for (int qa = 0; qa < 2; ++qa) {
    const int qg = q0 + w * 32 + qa * 16;
#pragma unroll
    for (int db = 0; db < 4; ++db)
#pragma unroll
      for (int r = 0; r < 4; ++r) {
        const int q = qg + quad * 4 + r;
        if (q < N_TOK)
          Opart[((size_t)sh * NKPAD + q) * 64 + db * 16 + l15] = f2bf(oacc[qa][db][r]);
      }
    if (quad == 0) {
      const int q = qg + l15;
      if (q < N_TOK) Lpart[sh * NKPAD + q] = l_r[qa];
    }
  }
}

// merge NSLICE key-slice partials -> bf16 Am [4160][384]
__global__ __launch_bounds__(256) void merge_kernel(const ushort* __restrict__ Opart,
                                                    const float* __restrict__ Lpart,
                                                    ushort* __restrict__ Am) {
  const int idx = blockIdx.x * 256 + threadIdx.x;     // u8 chunk index
  if (idx >= N_TOK * 48) return;
  const int q = idx / 48, c = (idx % 48) * 8;
  const int h = c >> 6, d = c & 63;
  float l = 0.f;
#pragma unroll
  for (int s = 0; s < NSLICE; ++s) l += Lpart[(s * 6 + h) * NKPAD + q];
  const float inv = 1.f / l;
  float o[8] = {0.f, 0.f, 0.f, 0.f, 0.f, 0.f, 0.f, 0.f};
#pragma unroll
  for (int s = 0; s < NSLICE; ++s) {
    const u8 v = *(const u8*)&Opart[((size_t)(s * 6 + h) * NKPAD + q) * 64 + d];
#pragma unroll
    for (int j = 0; j < 8; ++j) o[j] += bf2f(v[j]);
  }
  u8 r;
#pragma unroll
  for (int j = 0; j < 8; ++j) r[j] = f2bf(o[j] * inv);
  *(u8*)&Am[(size_t)q * C_DIM + c] = r;
}

// ---------------------------------------------------------------------------
extern "C" void kernel_launch(void* const* d_in, const int* in_sizes, int n_in,
                              void* d_out, int out_size, void* d_ws, size_t ws_size,
                              hipStream_t stream) {
  const float* x          = (const float*)d_in[0];
  const float* pos        = (const float*)d_in[1];
  const float* mask       = (const float*)d_in[2];
  const float* mask_block = (const float*)d_in[3];
  const float* Wq         = (const float*)d_in[4];
  const float* Wk         = (const float*)d_in[5];
  const float* Wv         = (const float*)d_in[6];
  const float* Wp         = (const float*)d_in[7];
  const float* bp         = (const float*)d_in[8];
  float* out = (float*)d_out;
  char* wsb = (char*)d_ws;

  float*  pooled_part = (float*)wsb;                // [64][384]
  float*  cnt_part    = (float*)(wsb + 98304);      // [64]
  int*    nk          = (int*)(wsb + 98560);
  int*    inv         = (int*)(wsb + 99072);        // [4099]
  ushort* Ak          = (ushort*)(wsb + 115712);    // [4160][384]
  ushort* Av          = (ushort*)(wsb + 3310592);   // [4160][384]
  ushort* Wb          = (ushort*)(wsb + 6505472);   // [4][384][384]
  ushort* Qh          = (ushort*)(wsb + 7685120);   // [6][4098][64]
  ushort* Kc          = (ushort*)(wsb + 10832384);  // [6][4160][64]
  ushort* Vt          = (ushort*)(wsb + 14027264);  // [6][64][4160]
  ushort* Am          = (ushort*)(wsb + 17222144);  // [4160][384]
  ushort* Op          = (ushort*)(wsb + 20417024);  // [30][4160][64]
  float*  Lp          = (float*)(wsb + 36391424);   // [30][4160]

  prep_kernel<<<dim3(357), dim3(256), 0, stream>>>(x, pos, Wq, Wk, Wv, Wp,
                                                   mask, mask_block, Ak, Av,
                                                   Wb, nk, inv,
                                                   pooled_part, cnt_part);
  back_kernel<<<dim3(1), dim3(384), 0, stream>>>(pooled_part, cnt_part, pos,
                                                 Ak, Av);
  gemm3_kernel<<<dim3(65, 18), 256, 0, stream>>>(Ak, Av, Wb, inv, Qh, Kc, Vt);
  attn_kernel<<<dim3(17, 6, NSLICE), 512, 0, stream>>>(Qh, Kc, Vt, nk, Op, Lp);
  merge_kernel<<<dim3(769), 256, 0, stream>>>(Op, Lp, Am);
  gemm_out_kernel<<<dim3(65, 6), 256, 0, stream>>>(Am, Wb + 3 * 147456, bp, out);
}